// Round 1
// baseline (1524.940 us; speedup 1.0000x reference)
//
#include <hip/hip_runtime.h>
#include <hip/hip_bf16.h>
#include <cstdint>
#include <cstddef>

typedef __bf16 bf16_t;
typedef __bf16 bf16x8 __attribute__((ext_vector_type(8)));
typedef __bf16 bf16x4v __attribute__((ext_vector_type(4)));
typedef float f32x4 __attribute__((ext_vector_type(4)));

#define B_SZ 4
#define L_SZ 4096
#define H_SZ 2048
#define R_SZ 256
#define LOG2E 1.44269504f

__device__ __forceinline__ f32x4 mfma16(bf16x8 a, bf16x8 b, f32x4 c) {
  return __builtin_amdgcn_mfma_f32_16x16x32_bf16(a, b, c, 0, 0, 0);
}

__device__ __forceinline__ float rmax16(float v) {
  v = fmaxf(v, __shfl_xor(v, 1, 16));
  v = fmaxf(v, __shfl_xor(v, 2, 16));
  v = fmaxf(v, __shfl_xor(v, 4, 16));
  v = fmaxf(v, __shfl_xor(v, 8, 16));
  return v;
}
__device__ __forceinline__ float rsum16(float v) {
  v += __shfl_xor(v, 1, 16);
  v += __shfl_xor(v, 2, 16);
  v += __shfl_xor(v, 4, 16);
  v += __shfl_xor(v, 8, 16);
  return v;
}

// ---------------- conversion kernels ----------------
__global__ void cvt_x_kernel(const float* __restrict__ x, bf16_t* __restrict__ xb, int n4) {
  int i = blockIdx.x * blockDim.x + threadIdx.x;
  const int stride = gridDim.x * blockDim.x;
  for (; i < n4; i += stride) {
    float4 v = reinterpret_cast<const float4*>(x)[i];
    bf16x4v o;
    o[0] = (bf16_t)v.x; o[1] = (bf16_t)v.y; o[2] = (bf16_t)v.z; o[3] = (bf16_t)v.w;
    reinterpret_cast<bf16x4v*>(xb)[i] = o;
  }
}

__global__ void cvt_w_kernel(const float* __restrict__ Ws, const float* __restrict__ Wa,
                             const float* __restrict__ Wo,
                             bf16_t* __restrict__ Wst, bf16_t* __restrict__ Wat,
                             bf16_t* __restrict__ Wob) {
  const int tid = blockIdx.x * blockDim.x + threadIdx.x;
  const int stride = gridDim.x * blockDim.x;
  // transpose [H, R] -> [R, H]
  for (int idx = tid; idx < R_SZ * H_SZ; idx += stride) {
    const int rr = idx >> 11;          // / H_SZ
    const int h  = idx & (H_SZ - 1);
    Wst[idx] = (bf16_t)Ws[h * R_SZ + rr];
    Wat[idx] = (bf16_t)Wa[h * R_SZ + rr];
  }
  for (int idx = tid; idx < H_SZ * H_SZ; idx += stride) {
    Wob[idx] = (bf16_t)Wo[idx];
  }
}

// ---------------- NT GEMM: C[m,n] = scale * sum_k A[m,k]*B[n,k] ----------------
// A row-major [M,K], B row-major [N,K], C bf16 row-major [M,ldc]. Tile 128x128, BK=64.
__global__ __launch_bounds__(256) void gemm_nt_kernel(
    const bf16_t* __restrict__ A, const bf16_t* __restrict__ B,
    bf16_t* __restrict__ C, int K, int ldc, float scale,
    long aBatch, long bBatch, long cBatch)
{
  __shared__ __attribute__((aligned(16))) bf16_t lA[128 * 64];
  __shared__ __attribute__((aligned(16))) bf16_t lB[128 * 64];
  const int t = threadIdx.x;
  const int l = t & 63;
  const int wv = t >> 6, wr = wv >> 1, wc = wv & 1;
  const char* Ab = (const char*)(A + (long)blockIdx.z * aBatch);
  const char* Bb = (const char*)(B + (long)blockIdx.z * bBatch);
  bf16_t* Cp = C + (long)blockIdx.z * cBatch;
  const int mBase = blockIdx.x * 128;
  const int nBase = blockIdx.y * 128;
  const long rowBytes = (long)K * 2;
  char* lAb = (char*)lA;
  char* lBb = (char*)lB;
  f32x4 acc[4][4] = {};
  const int nsteps = K >> 6;

  for (int ks = 0; ks < nsteps; ++ks) {
    const int kbyte = ks * 128;
    bf16x8 va[4], vb[4];
#pragma unroll
    for (int i = 0; i < 4; ++i) {
      const int d = t * 16 + i * 4096;
      const int row = d >> 7;
      const int inrow = d & 127;
      const int src = inrow ^ ((row & 7) << 4);  // pre-swizzled source, linear LDS dest
      va[i] = *(const bf16x8*)(Ab + (long)(mBase + row) * rowBytes + kbyte + src);
      vb[i] = *(const bf16x8*)(Bb + (long)(nBase + row) * rowBytes + kbyte + src);
    }
#pragma unroll
    for (int i = 0; i < 4; ++i) {
      const int d = t * 16 + i * 4096;
      *(bf16x8*)(lAb + d) = va[i];
      *(bf16x8*)(lBb + d) = vb[i];
    }
    __syncthreads();
#pragma unroll
    for (int kk = 0; kk < 2; ++kk) {
      bf16x8 af[4], bfv[4];
#pragma unroll
      for (int mt = 0; mt < 4; ++mt) {
        const int row = wr * 64 + mt * 16 + (l & 15);
        const int inr = (kk * 64 + ((l >> 4) * 16)) ^ ((row & 7) << 4);
        af[mt] = *(const bf16x8*)(lAb + row * 128 + inr);
      }
#pragma unroll
      for (int nt = 0; nt < 4; ++nt) {
        const int row = wc * 64 + nt * 16 + (l & 15);
        const int inr = (kk * 64 + ((l >> 4) * 16)) ^ ((row & 7) << 4);
        bfv[nt] = *(const bf16x8*)(lBb + row * 128 + inr);
      }
#pragma unroll
      for (int mt = 0; mt < 4; ++mt)
#pragma unroll
        for (int nt = 0; nt < 4; ++nt)
          acc[mt][nt] = mfma16(af[mt], bfv[nt], acc[mt][nt]);
    }
    __syncthreads();
  }
#pragma unroll
  for (int mt = 0; mt < 4; ++mt) {
#pragma unroll
    for (int nt = 0; nt < 4; ++nt) {
      const int row0 = mBase + wr * 64 + mt * 16 + ((l >> 4) * 4);
      const int col = nBase + wc * 64 + nt * 16 + (l & 15);
#pragma unroll
      for (int r = 0; r < 4; ++r) {
        Cp[(long)(row0 + r) * ldc + col] = (bf16_t)(acc[mt][nt][r] * scale);
      }
    }
  }
}

// ---------------- flash attention: y = softmax(Q K^T, causal) @ V' + bo ----------------
// Qb: [B*L, 256] bf16 (already scaled by 1/16), Kb: [B*L, 256] bf16
// VT: [B, H, L] bf16 (V'^T per batch), out fp32 [B*L, H]
// Block: 8 waves; q-tile 32 rows; strip = 8 k-subtiles of 64 (512 cols);
// wave w computes S for subtile w (shared P via LDS), owns 256 V' columns for PV.
__global__ __launch_bounds__(512, 2) void attn_kernel(
    const bf16_t* __restrict__ Qb, const bf16_t* __restrict__ Kb,
    const bf16_t* __restrict__ VT, const float* __restrict__ bo,
    float* __restrict__ out)
{
  __shared__ __attribute__((aligned(16))) char Plds[32 * 1024];  // P [32 rows][512 cols] bf16, swizzled
  __shared__ float rowmaxs[8][32];
  __shared__ float psums[8][32];
  __shared__ float m_sh[32];
  __shared__ float a_sh[32];
  __shared__ float l_sh[32];

  const int t = threadIdx.x;
  const int l = t & 63;
  const int w = t >> 6;
  const int b = blockIdx.y;
  const int qi = (int)(gridDim.x - 1 - blockIdx.x);  // big tiles first
  const int qs = qi * 32;
  const int obase = w * 256;
  const int lrow = (l >> 4) * 4;
  const int l15 = l & 15;
  const long qrow0 = (long)b * L_SZ;

  if (t < 32) { m_sh[t] = -1e30f; l_sh[t] = 0.0f; }
  __syncthreads();

  f32x4 acc[2][16] = {};

  const int nstrips = qs / 512 + 1;
  for (int s = 0; s < nstrips; ++s) {
    const int j00 = s * 512;
    const bool fin = (s == nstrips - 1);
    const int j0 = j00 + w * 64;
    const bool active = (j0 <= qs + 31);
    f32x4 sacc[2][4] = {};
    if (active) {
#pragma unroll
      for (int ksr = 0; ksr < 8; ++ksr) {
        bf16x8 aq[2], bk[4];
#pragma unroll
        for (int rt = 0; rt < 2; ++rt)
          aq[rt] = *(const bf16x8*)(Qb + (qrow0 + qs + rt * 16 + l15) * R_SZ + ksr * 32 + ((l >> 4) * 8));
#pragma unroll
        for (int nt = 0; nt < 4; ++nt)
          bk[nt] = *(const bf16x8*)(Kb + (qrow0 + j0 + nt * 16 + l15) * R_SZ + ksr * 32 + ((l >> 4) * 8));
#pragma unroll
        for (int rt = 0; rt < 2; ++rt)
#pragma unroll
          for (int nt = 0; nt < 4; ++nt)
            sacc[rt][nt] = mfma16(aq[rt], bk[nt], sacc[rt][nt]);
      }
      if (fin) {
#pragma unroll
        for (int rt = 0; rt < 2; ++rt)
#pragma unroll
          for (int nt = 0; nt < 4; ++nt)
#pragma unroll
            for (int r = 0; r < 4; ++r) {
              const int ii = qs + rt * 16 + lrow + r;
              const int jj = j0 + nt * 16 + l15;
              if (jj > ii) sacc[rt][nt][r] = -1e30f;
            }
      }
#pragma unroll
      for (int rt = 0; rt < 2; ++rt)
#pragma unroll
        for (int r = 0; r < 4; ++r) {
          float v = fmaxf(fmaxf(sacc[rt][0][r], sacc[rt][1][r]),
                          fmaxf(sacc[rt][2][r], sacc[rt][3][r]));
          v = rmax16(v);
          if (l15 == 0) rowmaxs[w][rt * 16 + lrow + r] = v;
        }
    } else {
      if (l15 == 0) {
#pragma unroll
        for (int rt = 0; rt < 2; ++rt)
#pragma unroll
          for (int r = 0; r < 4; ++r) rowmaxs[w][rt * 16 + lrow + r] = -1e30f;
      }
    }
    __syncthreads();  // bar1: rowmax visible
    if (w == 0 && l < 32) {
      float mt_ = rowmaxs[0][l];
#pragma unroll
      for (int ww = 1; ww < 8; ++ww) mt_ = fmaxf(mt_, rowmaxs[ww][l]);
      const float mo = m_sh[l];
      const float mn = fmaxf(mo, mt_);
      m_sh[l] = mn;
      a_sh[l] = exp2f((mo - mn) * LOG2E);
    }
    __syncthreads();  // bar2: m/alpha visible
    float ar[2][4], mr[2][4];
#pragma unroll
    for (int rt = 0; rt < 2; ++rt)
#pragma unroll
      for (int r = 0; r < 4; ++r) {
        ar[rt][r] = a_sh[rt * 16 + lrow + r];
        mr[rt][r] = m_sh[rt * 16 + lrow + r];
      }
#pragma unroll
    for (int rt = 0; rt < 2; ++rt)
#pragma unroll
      for (int ct = 0; ct < 16; ++ct)
#pragma unroll
        for (int r = 0; r < 4; ++r) acc[rt][ct][r] *= ar[rt][r];
    if (active) {
#pragma unroll
      for (int rt = 0; rt < 2; ++rt)
#pragma unroll
        for (int r = 0; r < 4; ++r) {
          float psv = 0.f;
          const int row = rt * 16 + lrow + r;
#pragma unroll
          for (int nt = 0; nt < 4; ++nt) {
            const float pv = exp2f((sacc[rt][nt][r] - mr[rt][r]) * LOG2E);
            psv += pv;
            const int jb = (w * 64 + nt * 16 + l15) * 2;
            *(bf16_t*)(Plds + row * 1024 + (jb ^ ((row & 7) << 4))) = (bf16_t)pv;
          }
          psv = rsum16(psv);
          if (l15 == 0) psums[w][row] = psv;
        }
    } else {
      if (l15 == 0) {
#pragma unroll
        for (int rt = 0; rt < 2; ++rt)
#pragma unroll
          for (int r = 0; r < 4; ++r) psums[w][rt * 16 + lrow + r] = 0.f;
      }
    }
    __syncthreads();  // bar3: P + psums visible
    if (w == 0 && l < 32) {
      float sl = 0.f;
#pragma unroll
      for (int ww = 0; ww < 8; ++ww) sl += psums[ww][l];
      l_sh[l] = a_sh[l] * l_sh[l] + sl;
    }
    const int nks = fin ? ((qs + 32 - j00 + 31) >> 5) : 16;
    for (int ksp = 0; ksp < nks; ++ksp) {
      bf16x8 pa[2];
#pragma unroll
      for (int rt = 0; rt < 2; ++rt) {
        const int row = rt * 16 + l15;
        const int inr = (ksp * 64 + ((l >> 4) * 16)) ^ ((row & 7) << 4);
        pa[rt] = *(const bf16x8*)(Plds + row * 1024 + inr);
      }
#pragma unroll
      for (int ct = 0; ct < 16; ++ct) {
        const bf16x8 bv = *(const bf16x8*)(VT +
            ((long)(b * H_SZ + obase + ct * 16 + l15)) * L_SZ + j00 + ksp * 32 + ((l >> 4) * 8));
        acc[0][ct] = mfma16(pa[0], bv, acc[0][ct]);
        acc[1][ct] = mfma16(pa[1], bv, acc[1][ct]);
      }
    }
    // next strip's P written only after its bar2 -> no extra barrier needed here
  }
  __syncthreads();
  float lr[2][4];
#pragma unroll
  for (int rt = 0; rt < 2; ++rt)
#pragma unroll
    for (int r = 0; r < 4; ++r) lr[rt][r] = 1.0f / l_sh[rt * 16 + lrow + r];
#pragma unroll
  for (int ct = 0; ct < 16; ++ct) {
    const int col = obase + ct * 16 + l15;
    const float bias = bo[col];
#pragma unroll
    for (int rt = 0; rt < 2; ++rt)
#pragma unroll
      for (int r = 0; r < 4; ++r) {
        out[(qrow0 + qs + rt * 16 + lrow + r) * H_SZ + col] =
            acc[rt][ct][r] * lr[rt][r] + bias;
      }
  }
}

extern "C" void kernel_launch(void* const* d_in, const int* in_sizes, int n_in,
                              void* d_out, int out_size, void* d_ws, size_t ws_size,
                              hipStream_t stream) {
  const float* x  = (const float*)d_in[0];
  const float* Ws = (const float*)d_in[1];
  const float* Wa = (const float*)d_in[2];
  const float* Wo = (const float*)d_in[3];
  const float* bo = (const float*)d_in[4];
  float* out = (float*)d_out;

  char* ws = (char*)d_ws;
  size_t off = 0;
  bf16_t* xb  = (bf16_t*)(ws + off); off += (size_t)B_SZ * L_SZ * H_SZ * 2;  // 64 MiB
  bf16_t* Wst = (bf16_t*)(ws + off); off += (size_t)R_SZ * H_SZ * 2;         // 1 MiB
  bf16_t* Wat = (bf16_t*)(ws + off); off += (size_t)R_SZ * H_SZ * 2;         // 1 MiB
  bf16_t* Wob = (bf16_t*)(ws + off); off += (size_t)H_SZ * H_SZ * 2;         // 8 MiB
  bf16_t* Qb  = (bf16_t*)(ws + off); off += (size_t)B_SZ * L_SZ * R_SZ * 2;  // 8 MiB
  bf16_t* Kb  = (bf16_t*)(ws + off); off += (size_t)B_SZ * L_SZ * R_SZ * 2;  // 8 MiB
  bf16_t* VT  = (bf16_t*)(ws + off); off += (size_t)B_SZ * H_SZ * L_SZ * 2;  // 64 MiB

  cvt_x_kernel<<<dim3(2048), dim3(256), 0, stream>>>(x, xb, B_SZ * L_SZ * H_SZ / 4);
  cvt_w_kernel<<<dim3(1024), dim3(256), 0, stream>>>(Ws, Wa, Wo, Wst, Wat, Wob);
  // Q = (x @ Ws) / 16  -> [16384, 256]
  gemm_nt_kernel<<<dim3(128, 2, 1), dim3(256), 0, stream>>>(xb, Wst, Qb, H_SZ, R_SZ, 0.0625f, 0, 0, 0);
  // K = x @ Wa -> [16384, 256]
  gemm_nt_kernel<<<dim3(128, 2, 1), dim3(256), 0, stream>>>(xb, Wat, Kb, H_SZ, R_SZ, 1.0f, 0, 0, 0);
  // V'^T[b][o][j] = sum_h Wo[o,h] * x[b,j,h] -> [B, H, L]
  gemm_nt_kernel<<<dim3(16, 32, 4), dim3(256), 0, stream>>>(Wob, xb, VT, H_SZ, L_SZ, 1.0f,
      0, (long)L_SZ * H_SZ, (long)H_SZ * L_SZ);
  attn_kernel<<<dim3(128, 4, 1), dim3(512), 0, stream>>>(Qb, Kb, VT, bo, out);
}

// Round 2
// 625.813 us; speedup vs baseline: 2.4367x; 2.4367x over previous
//
#include <hip/hip_runtime.h>
#include <hip/hip_bf16.h>
#include <cstdint>
#include <cstddef>

typedef __bf16 bf16_t;
typedef __bf16 bf16x8 __attribute__((ext_vector_type(8)));
typedef __bf16 bf16x4v __attribute__((ext_vector_type(4)));
typedef float f32x4 __attribute__((ext_vector_type(4)));

#define B_SZ 4
#define L_SZ 4096
#define H_SZ 2048
#define R_SZ 256
// exp(S) with S = acc/16  ->  2^(acc * log2(e)/16)
#define EXP_SC 0.090168440f
// E triangular-panel geometry: panel mi holds 128 rows x (mi+1)*128 cols bf16
#define E_BATCH_STRIDE 8650752L  // 16384 * 528 elements per batch

__device__ __forceinline__ f32x4 mfma16(bf16x8 a, bf16x8 b, f32x4 c) {
  return __builtin_amdgcn_mfma_f32_16x16x32_bf16(a, b, c, 0, 0, 0);
}

__device__ __forceinline__ float rsum16(float v) {
  v += __shfl_xor(v, 1, 16);
  v += __shfl_xor(v, 2, 16);
  v += __shfl_xor(v, 4, 16);
  v += __shfl_xor(v, 8, 16);
  return v;
}

// ---------------- conversion kernels ----------------
__global__ void cvt_x_kernel(const float* __restrict__ x, bf16_t* __restrict__ xb, int n4) {
  int i = blockIdx.x * blockDim.x + threadIdx.x;
  const int stride = gridDim.x * blockDim.x;
  for (; i < n4; i += stride) {
    float4 v = reinterpret_cast<const float4*>(x)[i];
    bf16x4v o;
    o[0] = (bf16_t)v.x; o[1] = (bf16_t)v.y; o[2] = (bf16_t)v.z; o[3] = (bf16_t)v.w;
    reinterpret_cast<bf16x4v*>(xb)[i] = o;
  }
}

__global__ void cvt_w_kernel(const float* __restrict__ Ws, const float* __restrict__ Wa,
                             const float* __restrict__ Wo,
                             bf16_t* __restrict__ Wst, bf16_t* __restrict__ Wat,
                             bf16_t* __restrict__ Wob, float* __restrict__ lsum) {
  const int tid = blockIdx.x * blockDim.x + threadIdx.x;
  const int stride = gridDim.x * blockDim.x;
  // transpose [H, R] -> [R, H]
  for (int idx = tid; idx < R_SZ * H_SZ; idx += stride) {
    const int rr = idx >> 11;          // / H_SZ
    const int h  = idx & (H_SZ - 1);
    Wst[idx] = (bf16_t)Ws[h * R_SZ + rr];
    Wat[idx] = (bf16_t)Wa[h * R_SZ + rr];
  }
  for (int idx = tid; idx < H_SZ * H_SZ; idx += stride) {
    Wob[idx] = (bf16_t)Wo[idx];
  }
  for (int idx = tid; idx < B_SZ * L_SZ; idx += stride) lsum[idx] = 0.0f;
}

// ---------------- NT GEMM: C[m,n] = scale * sum_k A[m,k]*B[n,k] ----------------
// A row-major [M,K], B row-major [N,K], C bf16 row-major [M,ldc]. Tile 128x128, BK=64.
__global__ __launch_bounds__(256) void gemm_nt_kernel(
    const bf16_t* __restrict__ A, const bf16_t* __restrict__ B,
    bf16_t* __restrict__ C, int K, int ldc, float scale,
    long aBatch, long bBatch, long cBatch)
{
  __shared__ __attribute__((aligned(16))) bf16_t lA[128 * 64];
  __shared__ __attribute__((aligned(16))) bf16_t lB[128 * 64];
  const int t = threadIdx.x;
  const int l = t & 63;
  const int wv = t >> 6, wr = wv >> 1, wc = wv & 1;
  const char* Ab = (const char*)(A + (long)blockIdx.z * aBatch);
  const char* Bb = (const char*)(B + (long)blockIdx.z * bBatch);
  bf16_t* Cp = C + (long)blockIdx.z * cBatch;
  const int mBase = blockIdx.x * 128;
  const int nBase = blockIdx.y * 128;
  const long rowBytes = (long)K * 2;
  char* lAb = (char*)lA;
  char* lBb = (char*)lB;
  f32x4 acc[4][4] = {};
  const int nsteps = K >> 6;

  for (int ks = 0; ks < nsteps; ++ks) {
    const int kbyte = ks * 128;
    bf16x8 va[4], vb[4];
#pragma unroll
    for (int i = 0; i < 4; ++i) {
      const int d = t * 16 + i * 4096;
      const int row = d >> 7;
      const int inrow = d & 127;
      const int src = inrow ^ ((row & 7) << 4);  // pre-swizzled source, linear LDS dest
      va[i] = *(const bf16x8*)(Ab + (long)(mBase + row) * rowBytes + kbyte + src);
      vb[i] = *(const bf16x8*)(Bb + (long)(nBase + row) * rowBytes + kbyte + src);
    }
#pragma unroll
    for (int i = 0; i < 4; ++i) {
      const int d = t * 16 + i * 4096;
      *(bf16x8*)(lAb + d) = va[i];
      *(bf16x8*)(lBb + d) = vb[i];
    }
    __syncthreads();
#pragma unroll
    for (int kk = 0; kk < 2; ++kk) {
      bf16x8 af[4], bfv[4];
#pragma unroll
      for (int mt = 0; mt < 4; ++mt) {
        const int row = wr * 64 + mt * 16 + (l & 15);
        const int inr = (kk * 64 + ((l >> 4) * 16)) ^ ((row & 7) << 4);
        af[mt] = *(const bf16x8*)(lAb + row * 128 + inr);
      }
#pragma unroll
      for (int nt = 0; nt < 4; ++nt) {
        const int row = wc * 64 + nt * 16 + (l & 15);
        const int inr = (kk * 64 + ((l >> 4) * 16)) ^ ((row & 7) << 4);
        bfv[nt] = *(const bf16x8*)(lBb + row * 128 + inr);
      }
#pragma unroll
      for (int mt = 0; mt < 4; ++mt)
#pragma unroll
        for (int nt = 0; nt < 4; ++nt)
          acc[mt][nt] = mfma16(af[mt], bfv[nt], acc[mt][nt]);
    }
    __syncthreads();
  }
#pragma unroll
  for (int mt = 0; mt < 4; ++mt) {
#pragma unroll
    for (int nt = 0; nt < 4; ++nt) {
      const int row0 = mBase + wr * 64 + mt * 16 + ((l >> 4) * 4);
      const int col = nBase + wc * 64 + nt * 16 + (l & 15);
#pragma unroll
      for (int r = 0; r < 4; ++r) {
        Cp[(long)(row0 + r) * ldc + col] = (bf16_t)(acc[mt][nt][r] * scale);
      }
    }
  }
}

// ---------------- pass 1: E = exp(Q K^T / 16) (causal), row sums -> lsum ----------------
// Qb/Kb: [B*L, 256] bf16 (unscaled). E: triangular panels. Grid (32, 32, 4), skip ji > mi.
__global__ __launch_bounds__(256) void epass_kernel(
    const bf16_t* __restrict__ Qb, const bf16_t* __restrict__ Kb,
    bf16_t* __restrict__ E, float* __restrict__ lsum)
{
  const int mi = blockIdx.x;
  const int ji = blockIdx.y;
  if (ji > mi) return;
  const int b = blockIdx.z;

  __shared__ __attribute__((aligned(16))) bf16_t lA[128 * 64];
  __shared__ __attribute__((aligned(16))) bf16_t lB[128 * 64];
  const int t = threadIdx.x;
  const int l = t & 63;
  const int wv = t >> 6, wr = wv >> 1, wc = wv & 1;
  const char* Ab = (const char*)(Qb + (long)b * L_SZ * R_SZ);
  const char* Bb = (const char*)(Kb + (long)b * L_SZ * R_SZ);
  const int mBase = mi * 128;
  const int nBase = ji * 128;
  const long rowBytes = R_SZ * 2;
  char* lAb = (char*)lA;
  char* lBb = (char*)lB;
  f32x4 acc[4][4] = {};

  for (int ks = 0; ks < 4; ++ks) {
    const int kbyte = ks * 128;
    bf16x8 va[4], vb[4];
#pragma unroll
    for (int i = 0; i < 4; ++i) {
      const int d = t * 16 + i * 4096;
      const int row = d >> 7;
      const int inrow = d & 127;
      const int src = inrow ^ ((row & 7) << 4);
      va[i] = *(const bf16x8*)(Ab + (long)(mBase + row) * rowBytes + kbyte + src);
      vb[i] = *(const bf16x8*)(Bb + (long)(nBase + row) * rowBytes + kbyte + src);
    }
#pragma unroll
    for (int i = 0; i < 4; ++i) {
      const int d = t * 16 + i * 4096;
      *(bf16x8*)(lAb + d) = va[i];
      *(bf16x8*)(lBb + d) = vb[i];
    }
    __syncthreads();
#pragma unroll
    for (int kk = 0; kk < 2; ++kk) {
      bf16x8 af[4], bfv[4];
#pragma unroll
      for (int mt = 0; mt < 4; ++mt) {
        const int row = wr * 64 + mt * 16 + (l & 15);
        const int inr = (kk * 64 + ((l >> 4) * 16)) ^ ((row & 7) << 4);
        af[mt] = *(const bf16x8*)(lAb + row * 128 + inr);
      }
#pragma unroll
      for (int nt = 0; nt < 4; ++nt) {
        const int row = wc * 64 + nt * 16 + (l & 15);
        const int inr = (kk * 64 + ((l >> 4) * 16)) ^ ((row & 7) << 4);
        bfv[nt] = *(const bf16x8*)(lBb + row * 128 + inr);
      }
#pragma unroll
      for (int mt = 0; mt < 4; ++mt)
#pragma unroll
        for (int nt = 0; nt < 4; ++nt)
          acc[mt][nt] = mfma16(af[mt], bfv[nt], acc[mt][nt]);
    }
    __syncthreads();
  }

  // epilogue: exp, causal mask, store bf16 panel, row-sum atomics
  bf16_t* Ep = E + (long)b * E_BATCH_STRIDE + 16384L * ((long)mi * (mi + 1) / 2);
  const int ldaE = (mi + 1) * 128;
  const int l15 = l & 15;
  const int lrow = (l >> 4) * 4;
#pragma unroll
  for (int mt = 0; mt < 4; ++mt) {
#pragma unroll
    for (int r = 0; r < 4; ++r) {
      const int row_in = wr * 64 + mt * 16 + lrow + r;
      const int ii = mBase + row_in;
      float s = 0.0f;
#pragma unroll
      for (int nt = 0; nt < 4; ++nt) {
        const int col_in = wc * 64 + nt * 16 + l15;
        const int jj = nBase + col_in;
        float p = exp2f(acc[mt][nt][r] * EXP_SC);
        if (jj > ii) p = 0.0f;
        Ep[(long)row_in * ldaE + ji * 128 + col_in] = (bf16_t)p;
        s += p;
      }
      s = rsum16(s);
      if (l15 == 0) atomicAdd(lsum + (long)b * L_SZ + ii, s);
    }
  }
}

// ---------------- pass 2: out = (E @ V'^T) / l + bo ----------------
// E triangular panels [B], VT [B, H, L], out fp32 [B*L, H]. Grid (32, 16, 4).
__global__ __launch_bounds__(256) void pv_kernel(
    const bf16_t* __restrict__ E, const bf16_t* __restrict__ VT,
    const float* __restrict__ lsum, const float* __restrict__ bo,
    float* __restrict__ out)
{
  const int mi = 31 - (int)blockIdx.x;  // big tiles first
  const int b = blockIdx.z;
  const int nBase = blockIdx.y * 128;

  __shared__ __attribute__((aligned(16))) bf16_t lA[128 * 64];
  __shared__ __attribute__((aligned(16))) bf16_t lB[128 * 64];
  const int t = threadIdx.x;
  const int l = t & 63;
  const int wv = t >> 6, wr = wv >> 1, wc = wv & 1;
  const int mBase = mi * 128;
  const int K = (mi + 1) * 128;
  const long aRowB = (long)K * 2;
  const long bRowB = L_SZ * 2;
  const char* Ab = (const char*)(E + (long)b * E_BATCH_STRIDE + 16384L * ((long)mi * (mi + 1) / 2));
  const char* Bb = (const char*)(VT + (long)b * H_SZ * L_SZ);
  char* lAb = (char*)lA;
  char* lBb = (char*)lB;
  f32x4 acc[4][4] = {};
  const int nsteps = K >> 6;

  for (int ks = 0; ks < nsteps; ++ks) {
    const int kbyte = ks * 128;
    bf16x8 va[4], vb[4];
#pragma unroll
    for (int i = 0; i < 4; ++i) {
      const int d = t * 16 + i * 4096;
      const int row = d >> 7;
      const int inrow = d & 127;
      const int src = inrow ^ ((row & 7) << 4);
      va[i] = *(const bf16x8*)(Ab + (long)row * aRowB + kbyte + src);
      vb[i] = *(const bf16x8*)(Bb + (long)(nBase + row) * bRowB + kbyte + src);
    }
#pragma unroll
    for (int i = 0; i < 4; ++i) {
      const int d = t * 16 + i * 4096;
      *(bf16x8*)(lAb + d) = va[i];
      *(bf16x8*)(lBb + d) = vb[i];
    }
    __syncthreads();
#pragma unroll
    for (int kk = 0; kk < 2; ++kk) {
      bf16x8 af[4], bfv[4];
#pragma unroll
      for (int mt = 0; mt < 4; ++mt) {
        const int row = wr * 64 + mt * 16 + (l & 15);
        const int inr = (kk * 64 + ((l >> 4) * 16)) ^ ((row & 7) << 4);
        af[mt] = *(const bf16x8*)(lAb + row * 128 + inr);
      }
#pragma unroll
      for (int nt = 0; nt < 4; ++nt) {
        const int row = wc * 64 + nt * 16 + (l & 15);
        const int inr = (kk * 64 + ((l >> 4) * 16)) ^ ((row & 7) << 4);
        bfv[nt] = *(const bf16x8*)(lBb + row * 128 + inr);
      }
#pragma unroll
      for (int mt = 0; mt < 4; ++mt)
#pragma unroll
        for (int nt = 0; nt < 4; ++nt)
          acc[mt][nt] = mfma16(af[mt], bfv[nt], acc[mt][nt]);
    }
    __syncthreads();
  }

  const int l15 = l & 15;
  const int lrow = (l >> 4) * 4;
#pragma unroll
  for (int mt = 0; mt < 4; ++mt) {
    const int row0 = wr * 64 + mt * 16 + lrow;
    float linv[4];
#pragma unroll
    for (int r = 0; r < 4; ++r)
      linv[r] = 1.0f / lsum[(long)b * L_SZ + mBase + row0 + r];
#pragma unroll
    for (int nt = 0; nt < 4; ++nt) {
      const int col = nBase + wc * 64 + nt * 16 + l15;
      const float bias = bo[col];
#pragma unroll
      for (int r = 0; r < 4; ++r) {
        out[((long)b * L_SZ + mBase + row0 + r) * H_SZ + col] =
            acc[mt][nt][r] * linv[r] + bias;
      }
    }
  }
}

extern "C" void kernel_launch(void* const* d_in, const int* in_sizes, int n_in,
                              void* d_out, int out_size, void* d_ws, size_t ws_size,
                              hipStream_t stream) {
  const float* x  = (const float*)d_in[0];
  const float* Ws = (const float*)d_in[1];
  const float* Wa = (const float*)d_in[2];
  const float* Wo = (const float*)d_in[3];
  const float* bo = (const float*)d_in[4];
  float* out = (float*)d_out;

  char* ws = (char*)d_ws;
  // layout (bytes):
  //   [0, 64M)        xb   (dead after V' GEMM)   -- aliased by E
  //   [64M, 65M)      Wst  (dead after QK GEMM)   -- aliased by E
  //   [65M, 66M)      Wat  (dead after QK GEMM)   -- aliased by E
  //   [66M, 74M)      Wob  (dead after V' GEMM)
  //   [74M, 82M)      Qb
  //   [82M, 90M)      Kb
  //   [90M, 154M)     VT
  //   [154M, +64K)    lsum
  bf16_t* xb  = (bf16_t*)(ws + 0);
  bf16_t* Wst = (bf16_t*)(ws + 67108864);
  bf16_t* Wat = (bf16_t*)(ws + 68157440);
  bf16_t* Wob = (bf16_t*)(ws + 69206016);
  bf16_t* Qb  = (bf16_t*)(ws + 77594624);
  bf16_t* Kb  = (bf16_t*)(ws + 85983232);
  bf16_t* VT  = (bf16_t*)(ws + 94371840);
  float*  lsum = (float*)(ws + 161480704);
  bf16_t* E   = (bf16_t*)(ws + 0);  // 69,206,016 bytes, exactly covers xb+Wst+Wat

  cvt_x_kernel<<<dim3(2048), dim3(256), 0, stream>>>(x, xb, B_SZ * L_SZ * H_SZ / 4);
  cvt_w_kernel<<<dim3(1024), dim3(256), 0, stream>>>(Ws, Wa, Wo, Wst, Wat, Wob, lsum);
  // Q = x @ Ws, K = x @ Wa (unscaled; 1/16 folded into EXP_SC) -> [16384, 256] each
  gemm_nt_kernel<<<dim3(128, 2, 2), dim3(256), 0, stream>>>(
      xb, Wst, Qb, H_SZ, R_SZ, 1.0f,
      0, (long)R_SZ * H_SZ, (long)B_SZ * L_SZ * R_SZ);
  // V'^T[b][o][j] = sum_h Wo[o,h] * x[b,j,h] -> [B, H, L]
  gemm_nt_kernel<<<dim3(16, 32, 4), dim3(256), 0, stream>>>(
      Wob, xb, VT, H_SZ, L_SZ, 1.0f,
      0, (long)L_SZ * H_SZ, (long)H_SZ * L_SZ);
  // pass 1: E = exp(QK^T/16) causal panels + row sums (runs after V': E aliases xb)
  epass_kernel<<<dim3(32, 32, 4), dim3(256), 0, stream>>>(Qb, Kb, E, lsum);
  // pass 2: out = E @ V'^T / l + bo
  pv_kernel<<<dim3(32, 16, 4), dim3(256), 0, stream>>>(E, VT, lsum, bo, out);
}

// Round 3
// 586.768 us; speedup vs baseline: 2.5989x; 1.0665x over previous
//
#include <hip/hip_runtime.h>
#include <hip/hip_bf16.h>
#include <cstdint>
#include <cstddef>

typedef __bf16 bf16_t;
typedef __bf16 bf16x8 __attribute__((ext_vector_type(8)));
typedef __bf16 bf16x4v __attribute__((ext_vector_type(4)));
typedef float f32x4 __attribute__((ext_vector_type(4)));

#define B_SZ 4
#define L_SZ 4096
#define H_SZ 2048
#define R_SZ 256
// exp(S) with S = acc/16  ->  2^(acc * log2(e)/16)
#define EXP_SC 0.090168440f
// E triangular-panel geometry: panel mi holds 128 rows x (mi+1)*128 cols bf16
#define E_BATCH_STRIDE 8650752L  // 16384 * 528 elements per batch

// async global->LDS, 16B per lane. LDS dest must be wave-uniform base (+lane*16 by HW).
#define GLDS16(gaddr, laddr)                                                     \
  __builtin_amdgcn_global_load_lds(                                             \
      (const __attribute__((address_space(1))) void*)(gaddr),                   \
      (__attribute__((address_space(3))) void*)(laddr), 16, 0, 0)

__device__ __forceinline__ f32x4 mfma16(bf16x8 a, bf16x8 b, f32x4 c) {
  return __builtin_amdgcn_mfma_f32_16x16x32_bf16(a, b, c, 0, 0, 0);
}

__device__ __forceinline__ float rsum16(float v) {
  v += __shfl_xor(v, 1, 16);
  v += __shfl_xor(v, 2, 16);
  v += __shfl_xor(v, 4, 16);
  v += __shfl_xor(v, 8, 16);
  return v;
}

// ---------------- conversion kernels ----------------
__global__ void cvt_x_kernel(const float* __restrict__ x, bf16_t* __restrict__ xb, int n4) {
  int i = blockIdx.x * blockDim.x + threadIdx.x;
  const int stride = gridDim.x * blockDim.x;
  for (; i < n4; i += stride) {
    float4 v = reinterpret_cast<const float4*>(x)[i];
    bf16x4v o;
    o[0] = (bf16_t)v.x; o[1] = (bf16_t)v.y; o[2] = (bf16_t)v.z; o[3] = (bf16_t)v.w;
    reinterpret_cast<bf16x4v*>(xb)[i] = o;
  }
}

__global__ void cvt_w_kernel(const float* __restrict__ Ws, const float* __restrict__ Wa,
                             const float* __restrict__ Wo,
                             bf16_t* __restrict__ Wst, bf16_t* __restrict__ Wat,
                             bf16_t* __restrict__ Wob, float* __restrict__ lsum) {
  const int tid = blockIdx.x * blockDim.x + threadIdx.x;
  const int stride = gridDim.x * blockDim.x;
  // transpose [H, R] -> [R, H]
  for (int idx = tid; idx < R_SZ * H_SZ; idx += stride) {
    const int rr = idx >> 11;          // / H_SZ
    const int h  = idx & (H_SZ - 1);
    Wst[idx] = (bf16_t)Ws[h * R_SZ + rr];
    Wat[idx] = (bf16_t)Wa[h * R_SZ + rr];
  }
  for (int idx = tid; idx < H_SZ * H_SZ; idx += stride) {
    Wob[idx] = (bf16_t)Wo[idx];
  }
  for (int idx = tid; idx < B_SZ * L_SZ; idx += stride) lsum[idx] = 0.0f;
}

// ---------------- NT GEMM: C[m,n] = scale * sum_k A[m,k]*B[n,k] ----------------
// A row-major [M,K], B row-major [N,K], C bf16 row-major [M,ldc]. Tile 128x128, BK=64.
__global__ __launch_bounds__(256) void gemm_nt_kernel(
    const bf16_t* __restrict__ A, const bf16_t* __restrict__ B,
    bf16_t* __restrict__ C, int K, int ldc, float scale,
    long aBatch, long bBatch, long cBatch)
{
  __shared__ __attribute__((aligned(16))) bf16_t lA[128 * 64];
  __shared__ __attribute__((aligned(16))) bf16_t lB[128 * 64];
  const int t = threadIdx.x;
  const int l = t & 63;
  const int wv = t >> 6, wr = wv >> 1, wc = wv & 1;
  const char* Ab = (const char*)(A + (long)blockIdx.z * aBatch);
  const char* Bb = (const char*)(B + (long)blockIdx.z * bBatch);
  bf16_t* Cp = C + (long)blockIdx.z * cBatch;
  const int mBase = blockIdx.x * 128;
  const int nBase = blockIdx.y * 128;
  const long rowBytes = (long)K * 2;
  char* lAb = (char*)lA;
  char* lBb = (char*)lB;
  f32x4 acc[4][4] = {};
  const int nsteps = K >> 6;

  for (int ks = 0; ks < nsteps; ++ks) {
    const int kbyte = ks * 128;
#pragma unroll
    for (int i = 0; i < 4; ++i) {
      const int d = t * 16 + i * 4096;
      const int row = d >> 7;
      const int src = (d & 127) ^ ((row & 7) << 4);  // pre-swizzled source, linear LDS dest
      const int ldst = wv * 1024 + i * 4096;          // wave-uniform LDS base
      GLDS16(Ab + (long)(mBase + row) * rowBytes + kbyte + src, lAb + ldst);
      GLDS16(Bb + (long)(nBase + row) * rowBytes + kbyte + src, lBb + ldst);
    }
    __syncthreads();
#pragma unroll
    for (int kk = 0; kk < 2; ++kk) {
      bf16x8 af[4], bfv[4];
#pragma unroll
      for (int mt = 0; mt < 4; ++mt) {
        const int row = wr * 64 + mt * 16 + (l & 15);
        const int inr = (kk * 64 + ((l >> 4) * 16)) ^ ((row & 7) << 4);
        af[mt] = *(const bf16x8*)(lAb + row * 128 + inr);
      }
#pragma unroll
      for (int nt = 0; nt < 4; ++nt) {
        const int row = wc * 64 + nt * 16 + (l & 15);
        const int inr = (kk * 64 + ((l >> 4) * 16)) ^ ((row & 7) << 4);
        bfv[nt] = *(const bf16x8*)(lBb + row * 128 + inr);
      }
#pragma unroll
      for (int mt = 0; mt < 4; ++mt)
#pragma unroll
        for (int nt = 0; nt < 4; ++nt)
          acc[mt][nt] = mfma16(af[mt], bfv[nt], acc[mt][nt]);
    }
    __syncthreads();
  }
#pragma unroll
  for (int mt = 0; mt < 4; ++mt) {
#pragma unroll
    for (int nt = 0; nt < 4; ++nt) {
      const int row0 = mBase + wr * 64 + mt * 16 + ((l >> 4) * 4);
      const int col = nBase + wc * 64 + nt * 16 + (l & 15);
#pragma unroll
      for (int r = 0; r < 4; ++r) {
        Cp[(long)(row0 + r) * ldc + col] = (bf16_t)(acc[mt][nt][r] * scale);
      }
    }
  }
}

// ---------------- pass 1: E = exp(Q K^T / 16) (causal), row sums -> lsum ----------------
// Qb/Kb: [B*L, 256] bf16 (unscaled). E: triangular panels. Grid (32, 32, 4), skip ji > mi.
__global__ __launch_bounds__(256) void epass_kernel(
    const bf16_t* __restrict__ Qb, const bf16_t* __restrict__ Kb,
    bf16_t* __restrict__ E, float* __restrict__ lsum)
{
  const int mi = blockIdx.x;
  const int ji = blockIdx.y;
  if (ji > mi) return;
  const int b = blockIdx.z;

  __shared__ __attribute__((aligned(16))) bf16_t lA[128 * 64];
  __shared__ __attribute__((aligned(16))) bf16_t lB[128 * 64];
  const int t = threadIdx.x;
  const int l = t & 63;
  const int wv = t >> 6, wr = wv >> 1, wc = wv & 1;
  const char* Ab = (const char*)(Qb + (long)b * L_SZ * R_SZ);
  const char* Bb = (const char*)(Kb + (long)b * L_SZ * R_SZ);
  const int mBase = mi * 128;
  const int nBase = ji * 128;
  const long rowBytes = R_SZ * 2;
  char* lAb = (char*)lA;
  char* lBb = (char*)lB;
  f32x4 acc[4][4] = {};

  for (int ks = 0; ks < 4; ++ks) {
    const int kbyte = ks * 128;
#pragma unroll
    for (int i = 0; i < 4; ++i) {
      const int d = t * 16 + i * 4096;
      const int row = d >> 7;
      const int src = (d & 127) ^ ((row & 7) << 4);
      const int ldst = wv * 1024 + i * 4096;
      GLDS16(Ab + (long)(mBase + row) * rowBytes + kbyte + src, lAb + ldst);
      GLDS16(Bb + (long)(nBase + row) * rowBytes + kbyte + src, lBb + ldst);
    }
    __syncthreads();
#pragma unroll
    for (int kk = 0; kk < 2; ++kk) {
      bf16x8 af[4], bfv[4];
#pragma unroll
      for (int mt = 0; mt < 4; ++mt) {
        const int row = wr * 64 + mt * 16 + (l & 15);
        const int inr = (kk * 64 + ((l >> 4) * 16)) ^ ((row & 7) << 4);
        af[mt] = *(const bf16x8*)(lAb + row * 128 + inr);
      }
#pragma unroll
      for (int nt = 0; nt < 4; ++nt) {
        const int row = wc * 64 + nt * 16 + (l & 15);
        const int inr = (kk * 64 + ((l >> 4) * 16)) ^ ((row & 7) << 4);
        bfv[nt] = *(const bf16x8*)(lBb + row * 128 + inr);
      }
#pragma unroll
      for (int mt = 0; mt < 4; ++mt)
#pragma unroll
        for (int nt = 0; nt < 4; ++nt)
          acc[mt][nt] = mfma16(af[mt], bfv[nt], acc[mt][nt]);
    }
    __syncthreads();
  }

  // epilogue: exp, causal mask, store bf16 panel, row-sum atomics
  bf16_t* Ep = E + (long)b * E_BATCH_STRIDE + 16384L * ((long)mi * (mi + 1) / 2);
  const int ldaE = (mi + 1) * 128;
  const int l15 = l & 15;
  const int lrow = (l >> 4) * 4;
#pragma unroll
  for (int mt = 0; mt < 4; ++mt) {
#pragma unroll
    for (int r = 0; r < 4; ++r) {
      const int row_in = wr * 64 + mt * 16 + lrow + r;
      const int ii = mBase + row_in;
      float s = 0.0f;
#pragma unroll
      for (int nt = 0; nt < 4; ++nt) {
        const int col_in = wc * 64 + nt * 16 + l15;
        const int jj = nBase + col_in;
        float p = exp2f(acc[mt][nt][r] * EXP_SC);
        if (jj > ii) p = 0.0f;
        Ep[(long)row_in * ldaE + ji * 128 + col_in] = (bf16_t)p;
        s += p;
      }
      s = rsum16(s);
      if (l15 == 0) atomicAdd(lsum + (long)b * L_SZ + ii, s);
    }
  }
}

// ---------------- pass 2: out = (E @ V'^T) / l + bo ----------------
// E triangular panels [B], VT [B, H, L], out fp32 [B*L, H]. Grid (32, 16, 4).
__global__ __launch_bounds__(256) void pv_kernel(
    const bf16_t* __restrict__ E, const bf16_t* __restrict__ VT,
    const float* __restrict__ lsum, const float* __restrict__ bo,
    float* __restrict__ out)
{
  const int mi = 31 - (int)blockIdx.x;  // big tiles first
  const int b = blockIdx.z;
  const int nBase = blockIdx.y * 128;

  __shared__ __attribute__((aligned(16))) bf16_t lA[128 * 64];
  __shared__ __attribute__((aligned(16))) bf16_t lB[128 * 64];
  const int t = threadIdx.x;
  const int l = t & 63;
  const int wv = t >> 6, wr = wv >> 1, wc = wv & 1;
  const int mBase = mi * 128;
  const int K = (mi + 1) * 128;
  const long aRowB = (long)K * 2;
  const long bRowB = L_SZ * 2;
  const char* Ab = (const char*)(E + (long)b * E_BATCH_STRIDE + 16384L * ((long)mi * (mi + 1) / 2));
  const char* Bb = (const char*)(VT + (long)b * H_SZ * L_SZ);
  char* lAb = (char*)lA;
  char* lBb = (char*)lB;
  f32x4 acc[4][4] = {};
  const int nsteps = K >> 6;

  for (int ks = 0; ks < nsteps; ++ks) {
    const int kbyte = ks * 128;
#pragma unroll
    for (int i = 0; i < 4; ++i) {
      const int d = t * 16 + i * 4096;
      const int row = d >> 7;
      const int src = (d & 127) ^ ((row & 7) << 4);
      const int ldst = wv * 1024 + i * 4096;
      GLDS16(Ab + (long)row * aRowB + kbyte + src, lAb + ldst);
      GLDS16(Bb + (long)(nBase + row) * bRowB + kbyte + src, lBb + ldst);
    }
    __syncthreads();
#pragma unroll
    for (int kk = 0; kk < 2; ++kk) {
      bf16x8 af[4], bfv[4];
#pragma unroll
      for (int mt = 0; mt < 4; ++mt) {
        const int row = wr * 64 + mt * 16 + (l & 15);
        const int inr = (kk * 64 + ((l >> 4) * 16)) ^ ((row & 7) << 4);
        af[mt] = *(const bf16x8*)(lAb + row * 128 + inr);
      }
#pragma unroll
      for (int nt = 0; nt < 4; ++nt) {
        const int row = wc * 64 + nt * 16 + (l & 15);
        const int inr = (kk * 64 + ((l >> 4) * 16)) ^ ((row & 7) << 4);
        bfv[nt] = *(const bf16x8*)(lBb + row * 128 + inr);
      }
#pragma unroll
      for (int mt = 0; mt < 4; ++mt)
#pragma unroll
        for (int nt = 0; nt < 4; ++nt)
          acc[mt][nt] = mfma16(af[mt], bfv[nt], acc[mt][nt]);
    }
    __syncthreads();
  }

  const int l15 = l & 15;
  const int lrow = (l >> 4) * 4;
#pragma unroll
  for (int mt = 0; mt < 4; ++mt) {
    const int row0 = wr * 64 + mt * 16 + lrow;
    float linv[4];
#pragma unroll
    for (int r = 0; r < 4; ++r)
      linv[r] = 1.0f / lsum[(long)b * L_SZ + mBase + row0 + r];
#pragma unroll
    for (int nt = 0; nt < 4; ++nt) {
      const int col = nBase + wc * 64 + nt * 16 + l15;
      const float bias = bo[col];
#pragma unroll
      for (int r = 0; r < 4; ++r) {
        out[((long)b * L_SZ + mBase + row0 + r) * H_SZ + col] =
            acc[mt][nt][r] * linv[r] + bias;
      }
    }
  }
}

extern "C" void kernel_launch(void* const* d_in, const int* in_sizes, int n_in,
                              void* d_out, int out_size, void* d_ws, size_t ws_size,
                              hipStream_t stream) {
  const float* x  = (const float*)d_in[0];
  const float* Ws = (const float*)d_in[1];
  const float* Wa = (const float*)d_in[2];
  const float* Wo = (const float*)d_in[3];
  const float* bo = (const float*)d_in[4];
  float* out = (float*)d_out;

  char* ws = (char*)d_ws;
  // layout (bytes):
  //   [0, 64M)        xb   (dead after V' GEMM)   -- aliased by E
  //   [64M, 65M)      Wst  (dead after QK GEMM)   -- aliased by E
  //   [65M, 66M)      Wat  (dead after QK GEMM)   -- aliased by E
  //   [66M, 74M)      Wob  (dead after V' GEMM)
  //   [74M, 82M)      Qb
  //   [82M, 90M)      Kb
  //   [90M, 154M)     VT
  //   [154M, +64K)    lsum
  bf16_t* xb  = (bf16_t*)(ws + 0);
  bf16_t* Wst = (bf16_t*)(ws + 67108864);
  bf16_t* Wat = (bf16_t*)(ws + 68157440);
  bf16_t* Wob = (bf16_t*)(ws + 69206016);
  bf16_t* Qb  = (bf16_t*)(ws + 77594624);
  bf16_t* Kb  = (bf16_t*)(ws + 85983232);
  bf16_t* VT  = (bf16_t*)(ws + 94371840);
  float*  lsum = (float*)(ws + 161480704);
  bf16_t* E   = (bf16_t*)(ws + 0);  // 69,206,016 bytes, exactly covers xb+Wst+Wat

  cvt_x_kernel<<<dim3(2048), dim3(256), 0, stream>>>(x, xb, B_SZ * L_SZ * H_SZ / 4);
  cvt_w_kernel<<<dim3(1024), dim3(256), 0, stream>>>(Ws, Wa, Wo, Wst, Wat, Wob, lsum);
  // Q = x @ Ws, K = x @ Wa (unscaled; 1/16 folded into EXP_SC) -> [16384, 256] each
  gemm_nt_kernel<<<dim3(128, 2, 2), dim3(256), 0, stream>>>(
      xb, Wst, Qb, H_SZ, R_SZ, 1.0f,
      0, (long)R_SZ * H_SZ, (long)B_SZ * L_SZ * R_SZ);
  // V'^T[b][o][j] = sum_h Wo[o,h] * x[b,j,h] -> [B, H, L]
  gemm_nt_kernel<<<dim3(16, 32, 4), dim3(256), 0, stream>>>(
      Wob, xb, VT, H_SZ, L_SZ, 1.0f,
      0, (long)L_SZ * H_SZ, (long)H_SZ * L_SZ);
  // pass 1: E = exp(QK^T/16) causal panels + row sums (runs after V': E aliases xb)
  epass_kernel<<<dim3(32, 32, 4), dim3(256), 0, stream>>>(Qb, Kb, E, lsum);
  // pass 2: out = E @ V'^T / l + bo
  pv_kernel<<<dim3(32, 16, 4), dim3(256), 0, stream>>>(E, VT, lsum, bo, out);
}

// Round 4
// 416.225 us; speedup vs baseline: 3.6637x; 1.4097x over previous
//
#include <hip/hip_runtime.h>
#include <hip/hip_bf16.h>
#include <cstdint>
#include <cstddef>

typedef __bf16 bf16_t;
typedef __bf16 bf16x8 __attribute__((ext_vector_type(8)));
typedef __bf16 bf16x4v __attribute__((ext_vector_type(4)));
typedef float f32x4 __attribute__((ext_vector_type(4)));

#define B_SZ 4
#define L_SZ 4096
#define H_SZ 2048
#define R_SZ 256
// exp(S) with S = acc/16  ->  2^(acc * log2(e)/16)
#define EXP_SC 0.090168440f
// E pair-panel geometry: pair P holds 256 rows x (P+1)*256 cols bf16
#define E2_ELEMS 8912896L   // 65536 * (1+2+...+16) elements per batch
#define E2_BYTES 17825792L

// async global->LDS, 16B per lane. LDS dest must be wave-uniform base (+lane*16 by HW).
#define GLDS16(gaddr, laddr)                                                    \
  __builtin_amdgcn_global_load_lds(                                             \
      (const __attribute__((address_space(1))) void*)(gaddr),                   \
      (__attribute__((address_space(3))) void*)(laddr), 16, 0, 0)

__device__ __forceinline__ f32x4 mfma16(bf16x8 a, bf16x8 b, f32x4 c) {
  return __builtin_amdgcn_mfma_f32_16x16x32_bf16(a, b, c, 0, 0, 0);
}

__device__ __forceinline__ float rsum16(float v) {
  v += __shfl_xor(v, 1, 16);
  v += __shfl_xor(v, 2, 16);
  v += __shfl_xor(v, 4, 16);
  v += __shfl_xor(v, 8, 16);
  return v;
}

// ---------------- conversion kernels ----------------
__global__ void cvt_x_kernel(const float* __restrict__ x, bf16_t* __restrict__ xb, int n4) {
  int i = blockIdx.x * blockDim.x + threadIdx.x;
  const int stride = gridDim.x * blockDim.x;
  for (; i < n4; i += stride) {
    float4 v = reinterpret_cast<const float4*>(x)[i];
    bf16x4v o;
    o[0] = (bf16_t)v.x; o[1] = (bf16_t)v.y; o[2] = (bf16_t)v.z; o[3] = (bf16_t)v.w;
    reinterpret_cast<bf16x4v*>(xb)[i] = o;
  }
}

__global__ void cvt_w_kernel(const float* __restrict__ Ws, const float* __restrict__ Wa,
                             const float* __restrict__ Wo,
                             bf16_t* __restrict__ Wst, bf16_t* __restrict__ Wat,
                             bf16_t* __restrict__ Wob, float* __restrict__ lsum) {
  const int tid = blockIdx.x * blockDim.x + threadIdx.x;
  const int stride = gridDim.x * blockDim.x;
  for (int idx = tid; idx < R_SZ * H_SZ; idx += stride) {
    const int rr = idx >> 11;
    const int h  = idx & (H_SZ - 1);
    Wst[idx] = (bf16_t)Ws[h * R_SZ + rr];
    Wat[idx] = (bf16_t)Wa[h * R_SZ + rr];
  }
  for (int idx = tid; idx < H_SZ * H_SZ; idx += stride) {
    Wob[idx] = (bf16_t)Wo[idx];
  }
  for (int idx = tid; idx < B_SZ * L_SZ; idx += stride) lsum[idx] = 0.0f;
}

// ================= 8-phase 256x256 GEMM core (plain-HIP HK-style schedule) =================
// C[m,n] = sum_k A[m,k] B[n,k], A row-major [256 rows from Ag], B row-major [256 rows from Bg],
// K = NT*64 (NT even, >= 4). 512 threads = 8 waves (2M x 4N). LDS 128 KiB dynamic.
// m-frag am (0..7) -> rows wr*16 + am*32 (+0..15); n-frag an (0..3) -> cols wc*16 + an*64 (+0..15).
// LDS: A region [0,64K): buf(32K) x half(16K); B region [64K,128K). Linear [128 rows][128 B] per
// half-slot, swizzle realized by pre-swizzled global source; reads XOR the same mask.

#define G8_STG(P, REGION, BUFOFF, HALF)                                        \
  GLDS16((P)[0], lds + (REGION) + (BUFOFF) + (HALF)*16384 + ldst0);            \
  GLDS16((P)[1], lds + (REGION) + (BUFOFF) + (HALF)*16384 + ldst1);            \
  (P)[0] += 128; (P)[1] += 128;

#define G8_LDA(MH, BO) {                                                       \
  const char* ap_ = lds + (BO) + (MH)*16384;                                   \
  fa[0][0] = *(const bf16x8*)(ap_ + aOff0);                                    \
  fa[0][1] = *(const bf16x8*)(ap_ + aOff1);                                    \
  fa[1][0] = *(const bf16x8*)(ap_ + 4096 + aOff0);                             \
  fa[1][1] = *(const bf16x8*)(ap_ + 4096 + aOff1);                             \
  fa[2][0] = *(const bf16x8*)(ap_ + 8192 + aOff0);                             \
  fa[2][1] = *(const bf16x8*)(ap_ + 8192 + aOff1);                             \
  fa[3][0] = *(const bf16x8*)(ap_ + 12288 + aOff0);                            \
  fa[3][1] = *(const bf16x8*)(ap_ + 12288 + aOff1); }

#define G8_LDB(NH, BO) {                                                       \
  const char* bp_ = lds + 65536 + (BO) + (NH)*16384;                           \
  fb[NH][0][0] = *(const bf16x8*)(bp_ + bOff0);                                \
  fb[NH][0][1] = *(const bf16x8*)(bp_ + bOff1);                                \
  fb[NH][1][0] = *(const bf16x8*)(bp_ + 8192 + bOff0);                         \
  fb[NH][1][1] = *(const bf16x8*)(bp_ + 8192 + bOff1); }

#define G8_MM1(AM, AN, MF, NH, J)                                              \
  acc[AM][AN] = mfma16(fa[MF][1], fb[NH][J][1],                                \
                 mfma16(fa[MF][0], fb[NH][J][0], acc[AM][AN]))

#define G8_MM(MH, NH)                                                          \
  G8_MM1((MH)*4+0, (NH)*2+0, 0, NH, 0); G8_MM1((MH)*4+0, (NH)*2+1, 0, NH, 1); \
  G8_MM1((MH)*4+1, (NH)*2+0, 1, NH, 0); G8_MM1((MH)*4+1, (NH)*2+1, 1, NH, 1); \
  G8_MM1((MH)*4+2, (NH)*2+0, 2, NH, 0); G8_MM1((MH)*4+2, (NH)*2+1, 2, NH, 1); \
  G8_MM1((MH)*4+3, (NH)*2+0, 3, NH, 0); G8_MM1((MH)*4+3, (NH)*2+1, 3, NH, 1)

#define G8_PHASE(LOADS, STAGES, WAITS, MH, NH)                                 \
  LOADS;                                                                       \
  STAGES;                                                                      \
  __builtin_amdgcn_sched_barrier(0);                                           \
  __builtin_amdgcn_s_barrier();                                                \
  asm volatile("s_waitcnt lgkmcnt(0)" ::: "memory");                           \
  __builtin_amdgcn_sched_barrier(0);                                           \
  __builtin_amdgcn_s_setprio(1);                                               \
  G8_MM(MH, NH);                                                               \
  __builtin_amdgcn_s_setprio(0);                                               \
  WAITS;                                                                       \
  __builtin_amdgcn_sched_barrier(0);                                           \
  __builtin_amdgcn_s_barrier();

__device__ __forceinline__ void gemm8_core(
    const char* Ag, const char* Bg, long aRowB, long bRowB, int NT,
    char* lds, f32x4 (&acc)[8][4])
{
  const int t = threadIdx.x;
  const int l = t & 63;
  const int wid = t >> 6;
  const int wr = wid >> 2;
  const int wc = wid & 3;
  const int l15 = l & 15;
  const int l4 = l >> 4;
  const int swzm = (l15 & 7) << 4;
  const int aOff0 = (wr * 16 + l15) * 128 + ((l4 * 16) ^ swzm);
  const int aOff1 = (wr * 16 + l15) * 128 + ((64 + l4 * 16) ^ swzm);
  const int bOff0 = (wc * 16 + l15) * 128 + ((l4 * 16) ^ swzm);
  const int bOff1 = (wc * 16 + l15) * 128 + ((64 + l4 * 16) ^ swzm);
  // staging: per-thread, 2 x 16B per half-tile; d = t*16 + i*8192 covers [0,16K) linear
  const int d0 = t * 16, d1 = t * 16 + 8192;
  const int r0 = d0 >> 7, r1 = d1 >> 7;
  const int s0 = (d0 & 127) ^ ((r0 & 7) << 4);
  const int s1 = (d1 & 127) ^ ((r1 & 7) << 4);
  const char* pA0[2] = { Ag + (long)r0 * aRowB + s0, Ag + (long)r1 * aRowB + s1 };
  const char* pA1[2] = { Ag + (long)(128 + r0) * aRowB + s0, Ag + (long)(128 + r1) * aRowB + s1 };
  const char* pB0[2] = { Bg + (long)r0 * bRowB + s0, Bg + (long)r1 * bRowB + s1 };
  const char* pB1[2] = { Bg + (long)(128 + r0) * bRowB + s0, Bg + (long)(128 + r1) * bRowB + s1 };
  const int ldst0 = wid * 1024, ldst1 = wid * 1024 + 8192;
  bf16x8 fa[4][2], fb[2][2][2];

  // prologue: stage tile0 (A0,B0,A1,B1) + tile1 (A0,B0); wait tile0; barrier
  G8_STG(pA0, 0, 0, 0);
  G8_STG(pB0, 65536, 0, 0);
  G8_STG(pA1, 0, 0, 1);
  G8_STG(pB1, 65536, 0, 1);
  G8_STG(pA0, 0, 32768, 0);
  G8_STG(pB0, 65536, 32768, 0);
  asm volatile("s_waitcnt vmcnt(4)" ::: "memory");
  __builtin_amdgcn_sched_barrier(0);
  __builtin_amdgcn_s_barrier();

  int bufOff = 0;
  for (int T = 0; T < NT - 2; ++T) {
    const int ob = bufOff ^ 32768;
    // q1: read A-h0 + B-h0 of tile T; stage (T+1).A1 -> other buf
    G8_PHASE(G8_LDA(0, bufOff) G8_LDB(0, bufOff), G8_STG(pA1, 0, ob, 1), , 0, 0);
    // q2: read B-h1; stage (T+1).B1
    G8_PHASE(G8_LDB(1, bufOff), G8_STG(pB1, 65536, ob, 1), , 0, 1);
    // q3: read A-h1; stage (T+2).A0 -> same buf (T's A-h0 free since q2-barrier)
    G8_PHASE(G8_LDA(1, bufOff), G8_STG(pA0, 0, bufOff, 0), , 1, 0);
    // q4: stage (T+2).B0; counted vmcnt guarantees tile T+1 fully landed
    G8_PHASE(, G8_STG(pB0, 65536, bufOff, 0),
             asm volatile("s_waitcnt vmcnt(4)" ::: "memory"), 1, 1);
    bufOff ^= 32768;
  }
  // T = NT-2: stage only (NT-1).A1/B1; drain at q4
  {
    const int ob = bufOff ^ 32768;
    G8_PHASE(G8_LDA(0, bufOff) G8_LDB(0, bufOff), G8_STG(pA1, 0, ob, 1), , 0, 0);
    G8_PHASE(G8_LDB(1, bufOff), G8_STG(pB1, 65536, ob, 1), , 0, 1);
    G8_PHASE(G8_LDA(1, bufOff), , , 1, 0);
    G8_PHASE(, , asm volatile("s_waitcnt vmcnt(0)" ::: "memory"), 1, 1);
    bufOff ^= 32768;
  }
  // T = NT-1: compute only
  {
    G8_PHASE(G8_LDA(0, bufOff) G8_LDB(0, bufOff), , , 0, 0);
    G8_PHASE(G8_LDB(1, bufOff), , , 0, 1);
    G8_PHASE(G8_LDA(1, bufOff), , , 1, 0);
    G8_PHASE(, , , 1, 1);
  }
}

// ---------------- QK projection: Qb = x @ Ws, Kb = x @ Wa (bf16 out) ----------------
__global__ __launch_bounds__(512) void qk8_kernel(
    const bf16_t* __restrict__ xb, const bf16_t* __restrict__ Wst,
    const bf16_t* __restrict__ Wat, bf16_t* __restrict__ Qb, bf16_t* __restrict__ Kb)
{
  extern __shared__ char lds[];
  const long mBase = (long)blockIdx.x * 256;
  const bf16_t* W = blockIdx.z ? Wat : Wst;
  bf16_t* Cp = blockIdx.z ? Kb : Qb;
  f32x4 acc[8][4] = {};
  gemm8_core((const char*)xb + mBase * (H_SZ * 2), (const char*)W,
             H_SZ * 2, H_SZ * 2, H_SZ / 64, lds, acc);
  const int t = threadIdx.x, l = t & 63, wid = t >> 6;
  const int wr = wid >> 2, wc = wid & 3, l15 = l & 15, l4 = l >> 4;
#pragma unroll
  for (int am = 0; am < 8; ++am) {
#pragma unroll
    for (int an = 0; an < 4; ++an) {
      const long row = mBase + wr * 16 + am * 32 + l4 * 4;
      const int col = wc * 16 + an * 64 + l15;
#pragma unroll
      for (int r = 0; r < 4; ++r)
        Cp[(row + r) * R_SZ + col] = (bf16_t)acc[am][an][r];
    }
  }
}

// ---------------- V' GEMM: VT[b][o][j] = sum_h Wo[o,h] x[b,j,h] (bf16 out) ----------------
__global__ __launch_bounds__(512) void vp8_kernel(
    const bf16_t* __restrict__ Wob, const bf16_t* __restrict__ xb, bf16_t* __restrict__ VT)
{
  extern __shared__ char lds[];
  const long mBase = (long)blockIdx.x * 256;   // o
  const long nBase = (long)blockIdx.y * 256;   // j
  const int b = blockIdx.z;
  f32x4 acc[8][4] = {};
  gemm8_core((const char*)Wob + mBase * (H_SZ * 2),
             (const char*)xb + ((long)b * L_SZ + nBase) * (H_SZ * 2),
             H_SZ * 2, H_SZ * 2, H_SZ / 64, lds, acc);
  bf16_t* Cp = VT + (long)b * H_SZ * L_SZ;
  const int t = threadIdx.x, l = t & 63, wid = t >> 6;
  const int wr = wid >> 2, wc = wid & 3, l15 = l & 15, l4 = l >> 4;
#pragma unroll
  for (int am = 0; am < 8; ++am) {
#pragma unroll
    for (int an = 0; an < 4; ++an) {
      const long row = mBase + wr * 16 + am * 32 + l4 * 4;
      const long col = nBase + wc * 16 + an * 64 + l15;
#pragma unroll
      for (int r = 0; r < 4; ++r)
        Cp[(row + r) * L_SZ + col] = (bf16_t)acc[am][an][r];
    }
  }
}

// ---------------- pass 1: E = exp(Q K^T / 16) (causal) into pair-panels, row sums ----------------
// Grid (32, 32, 4); tile (mi, ji) valid when ji <= (mi|1); jj>ii entries stored as 0.
__global__ __launch_bounds__(256) void epass_kernel(
    const bf16_t* __restrict__ Qb, const bf16_t* __restrict__ Kb,
    bf16_t* __restrict__ E, float* __restrict__ lsum)
{
  const int mi = blockIdx.x;
  const int ji = blockIdx.y;
  if (ji > (mi | 1)) return;
  const int b = blockIdx.z;

  __shared__ __attribute__((aligned(16))) bf16_t lA[128 * 64];
  __shared__ __attribute__((aligned(16))) bf16_t lB[128 * 64];
  const int t = threadIdx.x;
  const int l = t & 63;
  const int wv = t >> 6, wr = wv >> 1, wc = wv & 1;
  const char* Ab = (const char*)(Qb + (long)b * L_SZ * R_SZ);
  const char* Bb = (const char*)(Kb + (long)b * L_SZ * R_SZ);
  const int mBase = mi * 128;
  const int nBase = ji * 128;
  const long rowBytes = R_SZ * 2;
  char* lAb = (char*)lA;
  char* lBb = (char*)lB;
  f32x4 acc[4][4] = {};

  for (int ks = 0; ks < 4; ++ks) {
    const int kbyte = ks * 128;
#pragma unroll
    for (int i = 0; i < 4; ++i) {
      const int d = t * 16 + i * 4096;
      const int row = d >> 7;
      const int src = (d & 127) ^ ((row & 7) << 4);
      const int ldst = wv * 1024 + i * 4096;
      GLDS16(Ab + (long)(mBase + row) * rowBytes + kbyte + src, lAb + ldst);
      GLDS16(Bb + (long)(nBase + row) * rowBytes + kbyte + src, lBb + ldst);
    }
    __syncthreads();
#pragma unroll
    for (int kk = 0; kk < 2; ++kk) {
      bf16x8 af[4], bfv[4];
#pragma unroll
      for (int mt = 0; mt < 4; ++mt) {
        const int row = wr * 64 + mt * 16 + (l & 15);
        const int inr = (kk * 64 + ((l >> 4) * 16)) ^ ((row & 7) << 4);
        af[mt] = *(const bf16x8*)(lAb + row * 128 + inr);
      }
#pragma unroll
      for (int nt = 0; nt < 4; ++nt) {
        const int row = wc * 64 + nt * 16 + (l & 15);
        const int inr = (kk * 64 + ((l >> 4) * 16)) ^ ((row & 7) << 4);
        bfv[nt] = *(const bf16x8*)(lBb + row * 128 + inr);
      }
#pragma unroll
      for (int mt = 0; mt < 4; ++mt)
#pragma unroll
        for (int nt = 0; nt < 4; ++nt)
          acc[mt][nt] = mfma16(af[mt], bfv[nt], acc[mt][nt]);
    }
    __syncthreads();
  }

  // epilogue: exp, causal mask, store into pair-panel, row-sum atomics
  const int P = mi >> 1;
  bf16_t* Ep = E + (long)b * E2_ELEMS + 32768L * P * (P + 1);
  const long ldaE = (P + 1) * 256;
  const int rbase = (mi & 1) * 128;
  const int l15 = l & 15;
  const int lrow = (l >> 4) * 4;
#pragma unroll
  for (int mt = 0; mt < 4; ++mt) {
#pragma unroll
    for (int r = 0; r < 4; ++r) {
      const int row_in = wr * 64 + mt * 16 + lrow + r;
      const int ii = mBase + row_in;
      float s = 0.0f;
#pragma unroll
      for (int nt = 0; nt < 4; ++nt) {
        const int col_in = wc * 64 + nt * 16 + l15;
        const int jj = nBase + col_in;
        float p = exp2f(acc[mt][nt][r] * EXP_SC);
        if (jj > ii) p = 0.0f;
        Ep[(long)(rbase + row_in) * ldaE + ji * 128 + col_in] = (bf16_t)p;
        s += p;
      }
      s = rsum16(s);
      if (l15 == 0) atomicAdd(lsum + (long)b * L_SZ + ii, s);
    }
  }
}

// ---------------- pass 2: out = (E @ V'^T) / l + bo, paired tiles for balance ----------------
// Grid (8, 8, 4): pair p -> sub-tiles mt = 15-p and p (uniform 68 K-tiles per block).
__global__ __launch_bounds__(512) void pv8_kernel(
    const bf16_t* __restrict__ E, const bf16_t* __restrict__ VT,
    const float* __restrict__ lsum, const float* __restrict__ bo,
    float* __restrict__ out)
{
  extern __shared__ char lds[];
  const int pr = blockIdx.x;
  const int nBase = blockIdx.y * 256;
  const int b = blockIdx.z;
  const int t = threadIdx.x, l = t & 63, wid = t >> 6;
  const int wr = wid >> 2, wc = wid & 3, l15 = l & 15, l4 = l >> 4;

#pragma unroll
  for (int s = 0; s < 2; ++s) {
    const int mt = s ? pr : (15 - pr);
    f32x4 acc[8][4] = {};
    const char* Ag = (const char*)E + (long)b * E2_BYTES + 65536L * mt * (mt + 1);
    const char* Bg = (const char*)VT + ((long)b * H_SZ + nBase) * (L_SZ * 2);
    gemm8_core(Ag, Bg, (long)(mt + 1) * 512, L_SZ * 2, (mt + 1) * 4, lds, acc);
#pragma unroll
    for (int am = 0; am < 8; ++am) {
      const long rowG = (long)b * L_SZ + mt * 256 + wr * 16 + am * 32 + l4 * 4;
      float linv[4];
#pragma unroll
      for (int r = 0; r < 4; ++r) linv[r] = 1.0f / lsum[rowG + r];
#pragma unroll
      for (int an = 0; an < 4; ++an) {
        const int col = nBase + wc * 16 + an * 64 + l15;
        const float bias = bo[col];
#pragma unroll
        for (int r = 0; r < 4; ++r)
          out[(rowG + r) * H_SZ + col] = acc[am][an][r] * linv[r] + bias;
      }
    }
  }
}

extern "C" void kernel_launch(void* const* d_in, const int* in_sizes, int n_in,
                              void* d_out, int out_size, void* d_ws, size_t ws_size,
                              hipStream_t stream) {
  const float* x  = (const float*)d_in[0];
  const float* Ws = (const float*)d_in[1];
  const float* Wa = (const float*)d_in[2];
  const float* Wo = (const float*)d_in[3];
  const float* bo = (const float*)d_in[4];
  float* out = (float*)d_out;

  char* ws = (char*)d_ws;
  // layout (bytes):
  //   [0, 64M)        xb   (dead after V'/QK)  -- aliased by E pair-panels
  //   [64M, 65M)      Wst  (dead after QK)     -- aliased by E
  //   [65M, 66M)      Wat  (dead after QK)     -- aliased by E
  //   [66M, 74M)      Wob  (dead after V')     -- head aliased by E (E = 71.3MB < 74M)
  //   [74M, 82M)      Qb
  //   [82M, 90M)      Kb
  //   [90M, 154M)     VT
  //   [154M, +64K)    lsum
  bf16_t* xb  = (bf16_t*)(ws + 0);
  bf16_t* Wst = (bf16_t*)(ws + 67108864);
  bf16_t* Wat = (bf16_t*)(ws + 68157440);
  bf16_t* Wob = (bf16_t*)(ws + 69206016);
  bf16_t* Qb  = (bf16_t*)(ws + 77594624);
  bf16_t* Kb  = (bf16_t*)(ws + 85983232);
  bf16_t* VT  = (bf16_t*)(ws + 94371840);
  float*  lsum = (float*)(ws + 161480704);
  bf16_t* E   = (bf16_t*)(ws + 0);

  hipFuncSetAttribute((const void*)qk8_kernel, hipFuncAttributeMaxDynamicSharedMemorySize, 131072);
  hipFuncSetAttribute((const void*)vp8_kernel, hipFuncAttributeMaxDynamicSharedMemorySize, 131072);
  hipFuncSetAttribute((const void*)pv8_kernel, hipFuncAttributeMaxDynamicSharedMemorySize, 131072);

  cvt_x_kernel<<<dim3(2048), dim3(256), 0, stream>>>(x, xb, B_SZ * L_SZ * H_SZ / 4);
  cvt_w_kernel<<<dim3(1024), dim3(256), 0, stream>>>(Ws, Wa, Wo, Wst, Wat, Wob, lsum);
  // Q = x @ Ws, K = x @ Wa (unscaled; 1/16 folded into EXP_SC)
  qk8_kernel<<<dim3(64, 1, 2), dim3(512), 131072, stream>>>(xb, Wst, Wat, Qb, Kb);
  // V'^T[b][o][j] = sum_h Wo[o,h] * x[b,j,h]
  vp8_kernel<<<dim3(8, 16, 4), dim3(512), 131072, stream>>>(Wob, xb, VT);
  // pass 1: E = exp(QK^T/16) causal pair-panels + row sums (E aliases xb/W* — all dead now)
  epass_kernel<<<dim3(32, 32, 4), dim3(256), 0, stream>>>(Qb, Kb, E, lsum);
  // pass 2: out = E @ V'^T / l + bo
  pv8_kernel<<<dim3(8, 8, 4), dim3(512), 131072, stream>>>(E, VT, lsum, bo, out);
}

// Round 5
// 410.331 us; speedup vs baseline: 3.7164x; 1.0144x over previous
//
#include <hip/hip_runtime.h>
#include <hip/hip_bf16.h>
#include <cstdint>
#include <cstddef>

typedef __bf16 bf16_t;
typedef __bf16 bf16x8 __attribute__((ext_vector_type(8)));
typedef __bf16 bf16x4v __attribute__((ext_vector_type(4)));
typedef float f32x4 __attribute__((ext_vector_type(4)));

#define B_SZ 4
#define L_SZ 4096
#define H_SZ 2048
#define R_SZ 256
// exp(S) with S = acc/16  ->  2^(acc * log2(e)/16)
#define EXP_SC 0.090168440f
// E pair-panel geometry: pair P holds 256 rows x (P+1)*256 cols bf16
#define E2_ELEMS 8912896L   // 65536 * (1+2+...+16) elements per batch
#define E2_BYTES 17825792L

// async global->LDS, 16B per lane. LDS dest must be wave-uniform base (+lane*16 by HW).
#define GLDS16(gaddr, laddr)                                                    \
  __builtin_amdgcn_global_load_lds(                                             \
      (const __attribute__((address_space(1))) void*)(gaddr),                   \
      (__attribute__((address_space(3))) void*)(laddr), 16, 0, 0)

__device__ __forceinline__ f32x4 mfma16(bf16x8 a, bf16x8 b, f32x4 c) {
  return __builtin_amdgcn_mfma_f32_16x16x32_bf16(a, b, c, 0, 0, 0);
}

__device__ __forceinline__ float rsum16(float v) {
  v += __shfl_xor(v, 1, 16);
  v += __shfl_xor(v, 2, 16);
  v += __shfl_xor(v, 4, 16);
  v += __shfl_xor(v, 8, 16);
  return v;
}

// ---------------- conversion kernels ----------------
__global__ void cvt_x_kernel(const float* __restrict__ x, bf16_t* __restrict__ xb, int n4) {
  int i = blockIdx.x * blockDim.x + threadIdx.x;
  const int stride = gridDim.x * blockDim.x;
  for (; i < n4; i += stride) {
    float4 v = reinterpret_cast<const float4*>(x)[i];
    bf16x4v o;
    o[0] = (bf16_t)v.x; o[1] = (bf16_t)v.y; o[2] = (bf16_t)v.z; o[3] = (bf16_t)v.w;
    reinterpret_cast<bf16x4v*>(xb)[i] = o;
  }
}

__global__ void cvt_w_kernel(const float* __restrict__ Ws, const float* __restrict__ Wa,
                             const float* __restrict__ Wo,
                             bf16_t* __restrict__ Wst, bf16_t* __restrict__ Wat,
                             bf16_t* __restrict__ Wob, float* __restrict__ lsum) {
  const int tid = blockIdx.x * blockDim.x + threadIdx.x;
  const int stride = gridDim.x * blockDim.x;
  for (int idx = tid; idx < R_SZ * H_SZ; idx += stride) {
    const int rr = idx >> 11;
    const int h  = idx & (H_SZ - 1);
    Wst[idx] = (bf16_t)Ws[h * R_SZ + rr];
    Wat[idx] = (bf16_t)Wa[h * R_SZ + rr];
  }
  for (int idx = tid; idx < H_SZ * H_SZ; idx += stride) {
    Wob[idx] = (bf16_t)Wo[idx];
  }
  for (int idx = tid; idx < B_SZ * L_SZ; idx += stride) lsum[idx] = 0.0f;
}

// ================= 8-phase 256x256 GEMM core (plain-HIP HK-style schedule) =================
// C[m,n] = sum_k A[m,k] B[n,k], A row-major [256 rows from Ag], B row-major [256 rows from Bg],
// K = NT*64 (NT even, >= 4). 512 threads = 8 waves (2M x 4N). LDS 128 KiB dynamic.
// m-frag am (0..7) -> rows wr*16 + am*32 (+0..15); n-frag an (0..3) -> cols wc*16 + an*64 (+0..15).
// LDS: A region [0,64K): buf(32K) x half(16K); B region [64K,128K). Linear [128 rows][128 B] per
// half-slot, swizzle realized by pre-swizzled global source; reads XOR the same mask.

#define G8_STG(P, REGION, BUFOFF, HALF)                                        \
  GLDS16((P)[0], lds + (REGION) + (BUFOFF) + (HALF)*16384 + ldst0);            \
  GLDS16((P)[1], lds + (REGION) + (BUFOFF) + (HALF)*16384 + ldst1);            \
  (P)[0] += 128; (P)[1] += 128;

#define G8_LDA(MH, BO) {                                                       \
  const char* ap_ = lds + (BO) + (MH)*16384;                                   \
  fa[0][0] = *(const bf16x8*)(ap_ + aOff0);                                    \
  fa[0][1] = *(const bf16x8*)(ap_ + aOff1);                                    \
  fa[1][0] = *(const bf16x8*)(ap_ + 4096 + aOff0);                             \
  fa[1][1] = *(const bf16x8*)(ap_ + 4096 + aOff1);                             \
  fa[2][0] = *(const bf16x8*)(ap_ + 8192 + aOff0);                             \
  fa[2][1] = *(const bf16x8*)(ap_ + 8192 + aOff1);                             \
  fa[3][0] = *(const bf16x8*)(ap_ + 12288 + aOff0);                            \
  fa[3][1] = *(const bf16x8*)(ap_ + 12288 + aOff1); }

#define G8_LDB(NH, BO) {                                                       \
  const char* bp_ = lds + 65536 + (BO) + (NH)*16384;                           \
  fb[NH][0][0] = *(const bf16x8*)(bp_ + bOff0);                                \
  fb[NH][0][1] = *(const bf16x8*)(bp_ + bOff1);                                \
  fb[NH][1][0] = *(const bf16x8*)(bp_ + 8192 + bOff0);                         \
  fb[NH][1][1] = *(const bf16x8*)(bp_ + 8192 + bOff1); }

#define G8_MM1(AM, AN, MF, NH, J)                                              \
  acc[AM][AN] = mfma16(fa[MF][1], fb[NH][J][1],                                \
                 mfma16(fa[MF][0], fb[NH][J][0], acc[AM][AN]))

#define G8_MM(MH, NH)                                                          \
  G8_MM1((MH)*4+0, (NH)*2+0, 0, NH, 0); G8_MM1((MH)*4+0, (NH)*2+1, 0, NH, 1); \
  G8_MM1((MH)*4+1, (NH)*2+0, 1, NH, 0); G8_MM1((MH)*4+1, (NH)*2+1, 1, NH, 1); \
  G8_MM1((MH)*4+2, (NH)*2+0, 2, NH, 0); G8_MM1((MH)*4+2, (NH)*2+1, 2, NH, 1); \
  G8_MM1((MH)*4+3, (NH)*2+0, 3, NH, 0); G8_MM1((MH)*4+3, (NH)*2+1, 3, NH, 1)

#define G8_PHASE(LOADS, STAGES, WAITS, MH, NH)                                 \
  LOADS;                                                                       \
  STAGES;                                                                      \
  __builtin_amdgcn_sched_barrier(0);                                           \
  __builtin_amdgcn_s_barrier();                                                \
  asm volatile("s_waitcnt lgkmcnt(0)" ::: "memory");                           \
  __builtin_amdgcn_sched_barrier(0);                                           \
  __builtin_amdgcn_s_setprio(1);                                               \
  G8_MM(MH, NH);                                                               \
  __builtin_amdgcn_s_setprio(0);                                               \
  WAITS;                                                                       \
  __builtin_amdgcn_sched_barrier(0);                                           \
  __builtin_amdgcn_s_barrier();

__device__ __forceinline__ void gemm8_core(
    const char* Ag, const char* Bg, long aRowB, long bRowB, int NT,
    char* lds, f32x4 (&acc)[8][4])
{
  const int t = threadIdx.x;
  const int l = t & 63;
  const int wid = t >> 6;
  const int wr = wid >> 2;
  const int wc = wid & 3;
  const int l15 = l & 15;
  const int l4 = l >> 4;
  const int swzm = (l15 & 7) << 4;
  const int aOff0 = (wr * 16 + l15) * 128 + ((l4 * 16) ^ swzm);
  const int aOff1 = (wr * 16 + l15) * 128 + ((64 + l4 * 16) ^ swzm);
  const int bOff0 = (wc * 16 + l15) * 128 + ((l4 * 16) ^ swzm);
  const int bOff1 = (wc * 16 + l15) * 128 + ((64 + l4 * 16) ^ swzm);
  // staging: per-thread, 2 x 16B per half-tile; d = t*16 + i*8192 covers [0,16K) linear
  const int d0 = t * 16, d1 = t * 16 + 8192;
  const int r0 = d0 >> 7, r1 = d1 >> 7;
  const int s0 = (d0 & 127) ^ ((r0 & 7) << 4);
  const int s1 = (d1 & 127) ^ ((r1 & 7) << 4);
  const char* pA0[2] = { Ag + (long)r0 * aRowB + s0, Ag + (long)r1 * aRowB + s1 };
  const char* pA1[2] = { Ag + (long)(128 + r0) * aRowB + s0, Ag + (long)(128 + r1) * aRowB + s1 };
  const char* pB0[2] = { Bg + (long)r0 * bRowB + s0, Bg + (long)r1 * bRowB + s1 };
  const char* pB1[2] = { Bg + (long)(128 + r0) * bRowB + s0, Bg + (long)(128 + r1) * bRowB + s1 };
  const int ldst0 = wid * 1024, ldst1 = wid * 1024 + 8192;
  bf16x8 fa[4][2], fb[2][2][2];

  // prologue: stage tile0 (A0,B0,A1,B1) + tile1 (A0,B0); wait tile0; barrier
  G8_STG(pA0, 0, 0, 0);
  G8_STG(pB0, 65536, 0, 0);
  G8_STG(pA1, 0, 0, 1);
  G8_STG(pB1, 65536, 0, 1);
  G8_STG(pA0, 0, 32768, 0);
  G8_STG(pB0, 65536, 32768, 0);
  asm volatile("s_waitcnt vmcnt(4)" ::: "memory");
  __builtin_amdgcn_sched_barrier(0);
  __builtin_amdgcn_s_barrier();

  int bufOff = 0;
  for (int T = 0; T < NT - 2; ++T) {
    const int ob = bufOff ^ 32768;
    // q1: read A-h0 + B-h0 of tile T; stage (T+1).A1 -> other buf
    G8_PHASE(G8_LDA(0, bufOff) G8_LDB(0, bufOff), G8_STG(pA1, 0, ob, 1), , 0, 0);
    // q2: read B-h1; stage (T+1).B1
    G8_PHASE(G8_LDB(1, bufOff), G8_STG(pB1, 65536, ob, 1), , 0, 1);
    // q3: read A-h1; stage (T+2).A0 -> same buf (T's A-h0 free since q2-barrier)
    G8_PHASE(G8_LDA(1, bufOff), G8_STG(pA0, 0, bufOff, 0), , 1, 0);
    // q4: stage (T+2).B0; counted vmcnt guarantees tile T+1 fully landed
    G8_PHASE(, G8_STG(pB0, 65536, bufOff, 0),
             asm volatile("s_waitcnt vmcnt(4)" ::: "memory"), 1, 1);
    bufOff ^= 32768;
  }
  // T = NT-2: stage only (NT-1).A1/B1; drain at q4
  {
    const int ob = bufOff ^ 32768;
    G8_PHASE(G8_LDA(0, bufOff) G8_LDB(0, bufOff), G8_STG(pA1, 0, ob, 1), , 0, 0);
    G8_PHASE(G8_LDB(1, bufOff), G8_STG(pB1, 65536, ob, 1), , 0, 1);
    G8_PHASE(G8_LDA(1, bufOff), , , 1, 0);
    G8_PHASE(, , asm volatile("s_waitcnt vmcnt(0)" ::: "memory"), 1, 1);
    bufOff ^= 32768;
  }
  // T = NT-1: compute only
  {
    G8_PHASE(G8_LDA(0, bufOff) G8_LDB(0, bufOff), , , 0, 0);
    G8_PHASE(G8_LDB(1, bufOff), , , 0, 1);
    G8_PHASE(G8_LDA(1, bufOff), , , 1, 0);
    G8_PHASE(, , , 1, 1);
  }
}

// ---------------- QK projection: Qb = x @ Ws, Kb = x @ Wa (bf16 out) ----------------
__global__ __launch_bounds__(512) void qk8_kernel(
    const bf16_t* __restrict__ xb, const bf16_t* __restrict__ Wst,
    const bf16_t* __restrict__ Wat, bf16_t* __restrict__ Qb, bf16_t* __restrict__ Kb)
{
  extern __shared__ char lds[];
  const long mBase = (long)blockIdx.x * 256;
  const bf16_t* W = blockIdx.z ? Wat : Wst;
  bf16_t* Cp = blockIdx.z ? Kb : Qb;
  f32x4 acc[8][4] = {};
  gemm8_core((const char*)xb + mBase * (H_SZ * 2), (const char*)W,
             H_SZ * 2, H_SZ * 2, H_SZ / 64, lds, acc);
  const int t = threadIdx.x, l = t & 63, wid = t >> 6;
  const int wr = wid >> 2, wc = wid & 3, l15 = l & 15, l4 = l >> 4;
#pragma unroll
  for (int am = 0; am < 8; ++am) {
#pragma unroll
    for (int an = 0; an < 4; ++an) {
      const long row = mBase + wr * 16 + am * 32 + l4 * 4;
      const int col = wc * 16 + an * 64 + l15;
#pragma unroll
      for (int r = 0; r < 4; ++r)
        Cp[(row + r) * R_SZ + col] = (bf16_t)acc[am][an][r];
    }
  }
}

// ---------------- V' GEMM: VT[b][o][j] = sum_h Wo[o,h] x[b,j,h] (bf16 out) ----------------
// Flat grid 512 blocks; XCD-chunked swizzle: each XCD gets all 8 o-tiles x 8 j-tiles, one b.
__global__ __launch_bounds__(512) void vp8_kernel(
    const bf16_t* __restrict__ Wob, const bf16_t* __restrict__ xb, bf16_t* __restrict__ VT)
{
  extern __shared__ char lds[];
  const int f = blockIdx.x;                 // 0..511
  const int lg = (f & 7) * 64 + (f >> 3);   // bijective (512 = 8*64)
  const int xo = lg & 7;
  const int yj = (lg >> 3) & 15;
  const int b  = lg >> 7;
  const long mBase = (long)xo * 256;        // o
  const long nBase = (long)yj * 256;        // j
  f32x4 acc[8][4] = {};
  gemm8_core((const char*)Wob + mBase * (H_SZ * 2),
             (const char*)xb + ((long)b * L_SZ + nBase) * (H_SZ * 2),
             H_SZ * 2, H_SZ * 2, H_SZ / 64, lds, acc);
  bf16_t* Cp = VT + (long)b * H_SZ * L_SZ;
  const int t = threadIdx.x, l = t & 63, wid = t >> 6;
  const int wr = wid >> 2, wc = wid & 3, l15 = l & 15, l4 = l >> 4;
#pragma unroll
  for (int am = 0; am < 8; ++am) {
#pragma unroll
    for (int an = 0; an < 4; ++an) {
      const long row = mBase + wr * 16 + am * 32 + l4 * 4;
      const long col = nBase + wc * 16 + an * 64 + l15;
#pragma unroll
      for (int r = 0; r < 4; ++r)
        Cp[(row + r) * L_SZ + col] = (bf16_t)acc[am][an][r];
    }
  }
}

// ---------------- pass 1 (8-phase): E = exp(Q K^T / 16) (causal) pair-panels + row sums ----
// Grid (16,16,4): P = 256-row q-tile, Jp = 256-col k-tile, valid when Jp <= P. NT=4.
__global__ __launch_bounds__(512) void ep8_kernel(
    const bf16_t* __restrict__ Qb, const bf16_t* __restrict__ Kb,
    bf16_t* __restrict__ E, float* __restrict__ lsum)
{
  extern __shared__ char lds[];
  const int P = blockIdx.x;
  const int Jp = blockIdx.y;
  if (Jp > P) return;
  const int b = blockIdx.z;
  f32x4 acc[8][4] = {};
  gemm8_core((const char*)Qb + ((long)b * L_SZ + P * 256) * (R_SZ * 2),
             (const char*)Kb + ((long)b * L_SZ + Jp * 256) * (R_SZ * 2),
             R_SZ * 2, R_SZ * 2, R_SZ / 64, lds, acc);
  const int t = threadIdx.x, l = t & 63, wid = t >> 6;
  const int wr = wid >> 2, wc = wid & 3, l15 = l & 15, l4 = l >> 4;
  bf16_t* Ep = E + (long)b * E2_ELEMS + 32768L * P * (P + 1);
  const long ldaE = (long)(P + 1) * 256;
  float* lp = lsum + (long)b * L_SZ + P * 256;
  const bool diag = (Jp == P);
#pragma unroll
  for (int am = 0; am < 8; ++am) {
    const int rowi = wr * 16 + am * 32 + l4 * 4;   // 0..255 within pair rows
#pragma unroll
    for (int r = 0; r < 4; ++r) {
      float s = 0.0f;
#pragma unroll
      for (int an = 0; an < 4; ++an) {
        const int coli = wc * 16 + an * 64 + l15;
        float p = exp2f(acc[am][an][r] * EXP_SC);
        if (diag && coli > rowi + r) p = 0.0f;     // jj > ii (same 256-tile)
        Ep[(long)(rowi + r) * ldaE + Jp * 256 + coli] = (bf16_t)p;
        s += p;
      }
      s = rsum16(s);
      if (l15 == 0) atomicAdd(lp + rowi + r, s);
    }
  }
}

// ---------------- pass 2: out = (E @ V'^T) / l + bo, paired tiles for balance ----------------
// Flat grid 256; XCD-chunked swizzle: each XCD gets 4 pr-pairs x 8 j-slices, one b.
__global__ __launch_bounds__(512) void pv8_kernel(
    const bf16_t* __restrict__ E, const bf16_t* __restrict__ VT,
    const float* __restrict__ lsum, const float* __restrict__ bo,
    float* __restrict__ out)
{
  extern __shared__ char lds[];
  const int f = blockIdx.x;                 // 0..255
  const int lg = (f & 7) * 32 + (f >> 3);   // bijective (256 = 8*32)
  const int yj = lg & 7;
  const int pr = (lg >> 3) & 7;
  const int b  = lg >> 6;
  const int nBase = yj * 256;
  const int t = threadIdx.x, l = t & 63, wid = t >> 6;
  const int wr = wid >> 2, wc = wid & 3, l15 = l & 15, l4 = l >> 4;

#pragma unroll
  for (int s = 0; s < 2; ++s) {
    const int mt = s ? pr : (15 - pr);
    f32x4 acc[8][4] = {};
    const char* Ag = (const char*)E + (long)b * E2_BYTES + 65536L * mt * (mt + 1);
    const char* Bg = (const char*)VT + ((long)b * H_SZ + nBase) * (L_SZ * 2);
    gemm8_core(Ag, Bg, (long)(mt + 1) * 512, L_SZ * 2, (mt + 1) * 4, lds, acc);
#pragma unroll
    for (int am = 0; am < 8; ++am) {
      const long rowG = (long)b * L_SZ + mt * 256 + wr * 16 + am * 32 + l4 * 4;
      float linv[4];
#pragma unroll
      for (int r = 0; r < 4; ++r) linv[r] = 1.0f / lsum[rowG + r];
#pragma unroll
      for (int an = 0; an < 4; ++an) {
        const int col = nBase + wc * 16 + an * 64 + l15;
        const float bias = bo[col];
#pragma unroll
        for (int r = 0; r < 4; ++r)
          out[(rowG + r) * H_SZ + col] = acc[am][an][r] * linv[r] + bias;
      }
    }
  }
}

extern "C" void kernel_launch(void* const* d_in, const int* in_sizes, int n_in,
                              void* d_out, int out_size, void* d_ws, size_t ws_size,
                              hipStream_t stream) {
  const float* x  = (const float*)d_in[0];
  const float* Ws = (const float*)d_in[1];
  const float* Wa = (const float*)d_in[2];
  const float* Wo = (const float*)d_in[3];
  const float* bo = (const float*)d_in[4];
  float* out = (float*)d_out;

  char* ws = (char*)d_ws;
  // layout (bytes):
  //   [0, 64M)        xb   (dead after V'/QK)  -- aliased by E pair-panels
  //   [64M, 65M)      Wst  (dead after QK)     -- aliased by E
  //   [65M, 66M)      Wat  (dead after QK)     -- aliased by E
  //   [66M, 74M)      Wob  (dead after V')     -- head aliased by E (E = 71.3MB < 74M)
  //   [74M, 82M)      Qb
  //   [82M, 90M)      Kb
  //   [90M, 154M)     VT
  //   [154M, +64K)    lsum
  bf16_t* xb  = (bf16_t*)(ws + 0);
  bf16_t* Wst = (bf16_t*)(ws + 67108864);
  bf16_t* Wat = (bf16_t*)(ws + 68157440);
  bf16_t* Wob = (bf16_t*)(ws + 69206016);
  bf16_t* Qb  = (bf16_t*)(ws + 77594624);
  bf16_t* Kb  = (bf16_t*)(ws + 85983232);
  bf16_t* VT  = (bf16_t*)(ws + 94371840);
  float*  lsum = (float*)(ws + 161480704);
  bf16_t* E   = (bf16_t*)(ws + 0);

  hipFuncSetAttribute((const void*)qk8_kernel, hipFuncAttributeMaxDynamicSharedMemorySize, 131072);
  hipFuncSetAttribute((const void*)vp8_kernel, hipFuncAttributeMaxDynamicSharedMemorySize, 131072);
  hipFuncSetAttribute((const void*)ep8_kernel, hipFuncAttributeMaxDynamicSharedMemorySize, 131072);
  hipFuncSetAttribute((const void*)pv8_kernel, hipFuncAttributeMaxDynamicSharedMemorySize, 131072);

  cvt_x_kernel<<<dim3(2048), dim3(256), 0, stream>>>(x, xb, B_SZ * L_SZ * H_SZ / 4);
  cvt_w_kernel<<<dim3(1024), dim3(256), 0, stream>>>(Ws, Wa, Wo, Wst, Wat, Wob, lsum);
  // Q = x @ Ws, K = x @ Wa (unscaled; 1/16 folded into EXP_SC)
  qk8_kernel<<<dim3(64, 1, 2), dim3(512), 131072, stream>>>(xb, Wst, Wat, Qb, Kb);
  // V'^T[b][o][j] = sum_h Wo[o,h] * x[b,j,h]  (XCD-swizzled flat grid)
  vp8_kernel<<<dim3(512, 1, 1), dim3(512), 131072, stream>>>(Wob, xb, VT);
  // pass 1: E = exp(QK^T/16) causal pair-panels + row sums (E aliases xb/W* — all dead now)
  ep8_kernel<<<dim3(16, 16, 4), dim3(512), 131072, stream>>>(Qb, Kb, E, lsum);
  // pass 2: out = E @ V'^T / l + bo  (XCD-swizzled flat grid)
  pv8_kernel<<<dim3(256, 1, 1), dim3(512), 131072, stream>>>(E, VT, lsum, bo, out);
}

// Round 6
// 383.934 us; speedup vs baseline: 3.9719x; 1.0688x over previous
//
#include <hip/hip_runtime.h>
#include <hip/hip_bf16.h>
#include <cstdint>
#include <cstddef>
#include <cmath>

typedef __bf16 bf16_t;
typedef __bf16 bf16x8 __attribute__((ext_vector_type(8)));
typedef __bf16 bf16x4v __attribute__((ext_vector_type(4)));
typedef float f32x4 __attribute__((ext_vector_type(4)));

#define B_SZ 4
#define L_SZ 4096
#define H_SZ 2048
#define R_SZ 256
// exp(S) with S = acc/16  ->  2^(acc * log2(e)/16)
#define EXP_SC 0.090168440f
// E pair-panel geometry: pair P holds 256 rows x (P+1)*256 cols bf16
#define E2_ELEMS 8912896L   // 65536 * (1+2+...+16) elements per batch
#define E2_BYTES 17825792L

// async global->LDS, 16B per lane. LDS dest must be wave-uniform base (+lane*16 by HW).
#define GLDS16(gaddr, laddr)                                                    \
  __builtin_amdgcn_global_load_lds(                                             \
      (const __attribute__((address_space(1))) void*)(gaddr),                   \
      (__attribute__((address_space(3))) void*)(laddr), 16, 0, 0)

__device__ __forceinline__ f32x4 mfma16(bf16x8 a, bf16x8 b, f32x4 c) {
  return __builtin_amdgcn_mfma_f32_16x16x32_bf16(a, b, c, 0, 0, 0);
}

__device__ __forceinline__ float rsum16(float v) {
  v += __shfl_xor(v, 1, 16);
  v += __shfl_xor(v, 2, 16);
  v += __shfl_xor(v, 4, 16);
  v += __shfl_xor(v, 8, 16);
  return v;
}

// ---------------- fused conversion kernel ----------------
__global__ void conv_kernel(const float* __restrict__ x, const float* __restrict__ Ws,
                            const float* __restrict__ Wa, const float* __restrict__ Wo,
                            bf16_t* __restrict__ xb, bf16_t* __restrict__ Wst,
                            bf16_t* __restrict__ Wat, bf16_t* __restrict__ Wob,
                            float* __restrict__ lsum) {
  const int tid = blockIdx.x * blockDim.x + threadIdx.x;
  const int stride = gridDim.x * blockDim.x;
  const int n4 = B_SZ * L_SZ * H_SZ / 4;
  for (int i = tid; i < n4; i += stride) {
    float4 v = reinterpret_cast<const float4*>(x)[i];
    bf16x4v o;
    o[0] = (bf16_t)v.x; o[1] = (bf16_t)v.y; o[2] = (bf16_t)v.z; o[3] = (bf16_t)v.w;
    reinterpret_cast<bf16x4v*>(xb)[i] = o;
  }
  // transpose [H, R] -> [R, H]
  for (int idx = tid; idx < R_SZ * H_SZ; idx += stride) {
    const int rr = idx >> 11;
    const int h  = idx & (H_SZ - 1);
    Wst[idx] = (bf16_t)Ws[h * R_SZ + rr];
    Wat[idx] = (bf16_t)Wa[h * R_SZ + rr];
  }
  for (int idx = tid; idx < H_SZ * H_SZ; idx += stride) {
    Wob[idx] = (bf16_t)Wo[idx];
  }
  for (int idx = tid; idx < B_SZ * L_SZ; idx += stride) lsum[idx] = 0.0f;
}

// ================= 8-phase 256x256 GEMM core (plain-HIP HK-style schedule) =================
// C[m,n] = sum_k A[m,k] B[n,k], A row-major [256 rows from Ag], B row-major [256 rows from Bg],
// K = NT*64 (NT even, >= 4). 512 threads = 8 waves (2M x 4N). LDS 128 KiB dynamic.
// m-frag am (0..7) -> rows wr*16 + am*32 (+0..15); n-frag an (0..3) -> cols wc*16 + an*64 (+0..15).
// LDS: A region [0,64K): buf(32K) x half(16K); B region [64K,128K). Linear [128 rows][128 B] per
// half-slot, swizzle realized by pre-swizzled global source; reads XOR the same mask.
// NOTE (R6): no manual lgkmcnt(0) before the MFMA cluster — the ds_reads are plain C++ loads
// fully consumed by this phase's MFMAs, so the compiler emits fine-grained counted lgkmcnt,
// letting LDS read-return stream under the MFMA cluster. Slot validity is enforced purely by
// the counted vmcnt ("memory" asm) + end-of-phase sched_barrier(0)+s_barrier gates.

#define G8_STG(P, REGION, BUFOFF, HALF)                                        \
  GLDS16((P)[0], lds + (REGION) + (BUFOFF) + (HALF)*16384 + ldst0);            \
  GLDS16((P)[1], lds + (REGION) + (BUFOFF) + (HALF)*16384 + ldst1);            \
  (P)[0] += 128; (P)[1] += 128;

#define G8_LDA(MH, BO) {                                                       \
  const char* ap_ = lds + (BO) + (MH)*16384;                                   \
  fa[0][0] = *(const bf16x8*)(ap_ + aOff0);                                    \
  fa[0][1] = *(const bf16x8*)(ap_ + aOff1);                                    \
  fa[1][0] = *(const bf16x8*)(ap_ + 4096 + aOff0);                             \
  fa[1][1] = *(const bf16x8*)(ap_ + 4096 + aOff1);                             \
  fa[2][0] = *(const bf16x8*)(ap_ + 8192 + aOff0);                             \
  fa[2][1] = *(const bf16x8*)(ap_ + 8192 + aOff1);                             \
  fa[3][0] = *(const bf16x8*)(ap_ + 12288 + aOff0);                            \
  fa[3][1] = *(const bf16x8*)(ap_ + 12288 + aOff1); }

#define G8_LDB(NH, BO) {                                                       \
  const char* bp_ = lds + 65536 + (BO) + (NH)*16384;                           \
  fb[NH][0][0] = *(const bf16x8*)(bp_ + bOff0);                                \
  fb[NH][0][1] = *(const bf16x8*)(bp_ + bOff1);                                \
  fb[NH][1][0] = *(const bf16x8*)(bp_ + 8192 + bOff0);                         \
  fb[NH][1][1] = *(const bf16x8*)(bp_ + 8192 + bOff1); }

#define G8_MM1(AM, AN, MF, NH, J)                                              \
  acc[AM][AN] = mfma16(fa[MF][1], fb[NH][J][1],                                \
                 mfma16(fa[MF][0], fb[NH][J][0], acc[AM][AN]))

#define G8_MM(MH, NH)                                                          \
  G8_MM1((MH)*4+0, (NH)*2+0, 0, NH, 0); G8_MM1((MH)*4+0, (NH)*2+1, 0, NH, 1); \
  G8_MM1((MH)*4+1, (NH)*2+0, 1, NH, 0); G8_MM1((MH)*4+1, (NH)*2+1, 1, NH, 1); \
  G8_MM1((MH)*4+2, (NH)*2+0, 2, NH, 0); G8_MM1((MH)*4+2, (NH)*2+1, 2, NH, 1); \
  G8_MM1((MH)*4+3, (NH)*2+0, 3, NH, 0); G8_MM1((MH)*4+3, (NH)*2+1, 3, NH, 1)

#define G8_PHASE(LOADS, STAGES, WAITS, MH, NH)                                 \
  LOADS;                                                                       \
  STAGES;                                                                      \
  __builtin_amdgcn_sched_barrier(0);                                           \
  __builtin_amdgcn_s_barrier();                                                \
  __builtin_amdgcn_s_setprio(1);                                               \
  G8_MM(MH, NH);                                                               \
  __builtin_amdgcn_s_setprio(0);                                               \
  WAITS;                                                                       \
  __builtin_amdgcn_sched_barrier(0);                                           \
  __builtin_amdgcn_s_barrier();

__device__ __forceinline__ void gemm8_core(
    const char* Ag, const char* Bg, long aRowB, long bRowB, int NT,
    char* lds, f32x4 (&acc)[8][4])
{
  const int t = threadIdx.x;
  const int l = t & 63;
  const int wid = t >> 6;
  const int wr = wid >> 2;
  const int wc = wid & 3;
  const int l15 = l & 15;
  const int l4 = l >> 4;
  const int swzm = (l15 & 7) << 4;
  const int aOff0 = (wr * 16 + l15) * 128 + ((l4 * 16) ^ swzm);
  const int aOff1 = (wr * 16 + l15) * 128 + ((64 + l4 * 16) ^ swzm);
  const int bOff0 = (wc * 16 + l15) * 128 + ((l4 * 16) ^ swzm);
  const int bOff1 = (wc * 16 + l15) * 128 + ((64 + l4 * 16) ^ swzm);
  // staging: per-thread, 2 x 16B per half-tile; d = t*16 + i*8192 covers [0,16K) linear
  const int d0 = t * 16, d1 = t * 16 + 8192;
  const int r0 = d0 >> 7, r1 = d1 >> 7;
  const int s0 = (d0 & 127) ^ ((r0 & 7) << 4);
  const int s1 = (d1 & 127) ^ ((r1 & 7) << 4);
  const char* pA0[2] = { Ag + (long)r0 * aRowB + s0, Ag + (long)r1 * aRowB + s1 };
  const char* pA1[2] = { Ag + (long)(128 + r0) * aRowB + s0, Ag + (long)(128 + r1) * aRowB + s1 };
  const char* pB0[2] = { Bg + (long)r0 * bRowB + s0, Bg + (long)r1 * bRowB + s1 };
  const char* pB1[2] = { Bg + (long)(128 + r0) * bRowB + s0, Bg + (long)(128 + r1) * bRowB + s1 };
  const int ldst0 = wid * 1024, ldst1 = wid * 1024 + 8192;
  bf16x8 fa[4][2], fb[2][2][2];

  // prologue: stage tile0 (A0,B0,A1,B1) + tile1 (A0,B0); wait tile0; barrier
  G8_STG(pA0, 0, 0, 0);
  G8_STG(pB0, 65536, 0, 0);
  G8_STG(pA1, 0, 0, 1);
  G8_STG(pB1, 65536, 0, 1);
  G8_STG(pA0, 0, 32768, 0);
  G8_STG(pB0, 65536, 32768, 0);
  asm volatile("s_waitcnt vmcnt(4)" ::: "memory");
  __builtin_amdgcn_sched_barrier(0);
  __builtin_amdgcn_s_barrier();

  int bufOff = 0;
  for (int T = 0; T < NT - 2; ++T) {
    const int ob = bufOff ^ 32768;
    // q1: read A-h0 + B-h0 of tile T; stage (T+1).A1 -> other buf
    G8_PHASE(G8_LDA(0, bufOff) G8_LDB(0, bufOff), G8_STG(pA1, 0, ob, 1), , 0, 0);
    // q2: read B-h1; stage (T+1).B1
    G8_PHASE(G8_LDB(1, bufOff), G8_STG(pB1, 65536, ob, 1), , 0, 1);
    // q3: read A-h1; stage (T+2).A0 -> same buf (T's A-h0 free since q2-barrier)
    G8_PHASE(G8_LDA(1, bufOff), G8_STG(pA0, 0, bufOff, 0), , 1, 0);
    // q4: stage (T+2).B0; counted vmcnt guarantees tile T+1 fully landed
    G8_PHASE(, G8_STG(pB0, 65536, bufOff, 0),
             asm volatile("s_waitcnt vmcnt(4)" ::: "memory"), 1, 1);
    bufOff ^= 32768;
  }
  // T = NT-2: stage only (NT-1).A1/B1; drain at q4
  {
    const int ob = bufOff ^ 32768;
    G8_PHASE(G8_LDA(0, bufOff) G8_LDB(0, bufOff), G8_STG(pA1, 0, ob, 1), , 0, 0);
    G8_PHASE(G8_LDB(1, bufOff), G8_STG(pB1, 65536, ob, 1), , 0, 1);
    G8_PHASE(G8_LDA(1, bufOff), , , 1, 0);
    G8_PHASE(, , asm volatile("s_waitcnt vmcnt(0)" ::: "memory"), 1, 1);
    bufOff ^= 32768;
  }
  // T = NT-1: compute only
  {
    G8_PHASE(G8_LDA(0, bufOff) G8_LDB(0, bufOff), , , 0, 0);
    G8_PHASE(G8_LDB(1, bufOff), , , 0, 1);
    G8_PHASE(G8_LDA(1, bufOff), , , 1, 0);
    G8_PHASE(, , , 1, 1);
  }
}

// ---------------- fused V'+QK GEMM kernel ----------------
// Flat grid 640 blocks. f < 128: QK projection (proj = f>>6, mtile = f&63; short blocks first
// so the dispatcher fills CU tails). f >= 128: V' GEMM with XCD-chunked swizzle.
__global__ __launch_bounds__(512) void vq8_kernel(
    const bf16_t* __restrict__ Wob, const bf16_t* __restrict__ xb, bf16_t* __restrict__ VT,
    const bf16_t* __restrict__ Wst, const bf16_t* __restrict__ Wat,
    bf16_t* __restrict__ Qb, bf16_t* __restrict__ Kb)
{
  extern __shared__ char lds[];
  const int f = blockIdx.x;
  const int t = threadIdx.x, l = t & 63, wid = t >> 6;
  const int wr = wid >> 2, wc = wid & 3, l15 = l & 15, l4 = l >> 4;
  if (f < 128) {
    const int proj = f >> 6;
    const long mBase = (long)(f & 63) * 256;
    const bf16_t* W = proj ? Wat : Wst;
    bf16_t* Cp = proj ? Kb : Qb;
    f32x4 acc[8][4] = {};
    gemm8_core((const char*)xb + mBase * (H_SZ * 2), (const char*)W,
               H_SZ * 2, H_SZ * 2, H_SZ / 64, lds, acc);
#pragma unroll
    for (int am = 0; am < 8; ++am) {
#pragma unroll
      for (int an = 0; an < 4; ++an) {
        const long row = mBase + wr * 16 + am * 32 + l4 * 4;
        const int col = wc * 16 + an * 64 + l15;
#pragma unroll
        for (int r = 0; r < 4; ++r)
          Cp[(row + r) * R_SZ + col] = (bf16_t)acc[am][an][r];
      }
    }
  } else {
    const int g = f - 128;                    // 0..511
    const int lg = (g & 7) * 64 + (g >> 3);   // bijective (512 = 8*64)
    const int xo = lg & 7;
    const int yj = (lg >> 3) & 15;
    const int b  = lg >> 7;
    const long mBase = (long)xo * 256;        // o
    const long nBase = (long)yj * 256;        // j
    f32x4 acc[8][4] = {};
    gemm8_core((const char*)Wob + mBase * (H_SZ * 2),
               (const char*)xb + ((long)b * L_SZ + nBase) * (H_SZ * 2),
               H_SZ * 2, H_SZ * 2, H_SZ / 64, lds, acc);
    bf16_t* Cp = VT + (long)b * H_SZ * L_SZ;
#pragma unroll
    for (int am = 0; am < 8; ++am) {
#pragma unroll
      for (int an = 0; an < 4; ++an) {
        const long row = mBase + wr * 16 + am * 32 + l4 * 4;
        const long col = nBase + wc * 16 + an * 64 + l15;
#pragma unroll
        for (int r = 0; r < 4; ++r)
          Cp[(row + r) * L_SZ + col] = (bf16_t)acc[am][an][r];
      }
    }
  }
}

// ---------------- pass 1 (8-phase): E = exp(Q K^T / 16) (causal) pair-panels + row sums ----
// Flat grid 544 (= 4 b x 136 triangular tiles), XCD-chunked so same-Q-panel blocks share an L2.
__global__ __launch_bounds__(512) void ep8_kernel(
    const bf16_t* __restrict__ Qb, const bf16_t* __restrict__ Kb,
    bf16_t* __restrict__ E, float* __restrict__ lsum)
{
  extern __shared__ char lds[];
  const int f = blockIdx.x;                  // 0..543
  const int lg = (f & 7) * 68 + (f >> 3);    // bijective (544 = 8*68)
  const int b = lg / 136;
  const int t136 = lg - b * 136;
  int P = (int)((sqrtf((float)(8 * t136 + 1)) - 1.0f) * 0.5f);
  while ((P + 1) * (P + 2) / 2 <= t136) ++P;
  while (P * (P + 1) / 2 > t136) --P;
  const int Jp = t136 - P * (P + 1) / 2;     // 0..P

  f32x4 acc[8][4] = {};
  gemm8_core((const char*)Qb + ((long)b * L_SZ + P * 256) * (R_SZ * 2),
             (const char*)Kb + ((long)b * L_SZ + Jp * 256) * (R_SZ * 2),
             R_SZ * 2, R_SZ * 2, R_SZ / 64, lds, acc);
  const int t = threadIdx.x, l = t & 63, wid = t >> 6;
  const int wr = wid >> 2, wc = wid & 3, l15 = l & 15, l4 = l >> 4;
  bf16_t* Ep = E + (long)b * E2_ELEMS + 32768L * P * (P + 1);
  const long ldaE = (long)(P + 1) * 256;
  float* lp = lsum + (long)b * L_SZ + P * 256;
  const bool diag = (Jp == P);
#pragma unroll
  for (int am = 0; am < 8; ++am) {
    const int rowi = wr * 16 + am * 32 + l4 * 4;   // 0..255 within pair rows
#pragma unroll
    for (int r = 0; r < 4; ++r) {
      float s = 0.0f;
#pragma unroll
      for (int an = 0; an < 4; ++an) {
        const int coli = wc * 16 + an * 64 + l15;
        float p = exp2f(acc[am][an][r] * EXP_SC);
        if (diag && coli > rowi + r) p = 0.0f;     // jj > ii (same 256-tile)
        Ep[(long)(rowi + r) * ldaE + Jp * 256 + coli] = (bf16_t)p;
        s += p;
      }
      s = rsum16(s);
      if (l15 == 0) atomicAdd(lp + rowi + r, s);
    }
  }
}

// ---------------- pass 2: out = (E @ V'^T) / l + bo, paired tiles for balance ----------------
// Flat grid 256; XCD-chunked swizzle: each XCD gets 4 pr-pairs x 8 j-slices, one b.
__global__ __launch_bounds__(512) void pv8_kernel(
    const bf16_t* __restrict__ E, const bf16_t* __restrict__ VT,
    const float* __restrict__ lsum, const float* __restrict__ bo,
    float* __restrict__ out)
{
  extern __shared__ char lds[];
  const int f = blockIdx.x;                 // 0..255
  const int lg = (f & 7) * 32 + (f >> 3);   // bijective (256 = 8*32)
  const int yj = lg & 7;
  const int pr = (lg >> 3) & 7;
  const int b  = lg >> 6;
  const int nBase = yj * 256;
  const int t = threadIdx.x, l = t & 63, wid = t >> 6;
  const int wr = wid >> 2, wc = wid & 3, l15 = l & 15, l4 = l >> 4;

#pragma unroll
  for (int s = 0; s < 2; ++s) {
    const int mt = s ? pr : (15 - pr);
    f32x4 acc[8][4] = {};
    const char* Ag = (const char*)E + (long)b * E2_BYTES + 65536L * mt * (mt + 1);
    const char* Bg = (const char*)VT + ((long)b * H_SZ + nBase) * (L_SZ * 2);
    gemm8_core(Ag, Bg, (long)(mt + 1) * 512, L_SZ * 2, (mt + 1) * 4, lds, acc);
#pragma unroll
    for (int am = 0; am < 8; ++am) {
      const long rowG = (long)b * L_SZ + mt * 256 + wr * 16 + am * 32 + l4 * 4;
      float linv[4];
#pragma unroll
      for (int r = 0; r < 4; ++r) linv[r] = 1.0f / lsum[rowG + r];
#pragma unroll
      for (int an = 0; an < 4; ++an) {
        const int col = nBase + wc * 16 + an * 64 + l15;
        const float bias = bo[col];
#pragma unroll
        for (int r = 0; r < 4; ++r)
          out[(rowG + r) * H_SZ + col] = acc[am][an][r] * linv[r] + bias;
      }
    }
  }
}

extern "C" void kernel_launch(void* const* d_in, const int* in_sizes, int n_in,
                              void* d_out, int out_size, void* d_ws, size_t ws_size,
                              hipStream_t stream) {
  const float* x  = (const float*)d_in[0];
  const float* Ws = (const float*)d_in[1];
  const float* Wa = (const float*)d_in[2];
  const float* Wo = (const float*)d_in[3];
  const float* bo = (const float*)d_in[4];
  float* out = (float*)d_out;

  char* ws = (char*)d_ws;
  // layout (bytes):
  //   [0, 64M)        xb   (dead after V'/QK)  -- aliased by E pair-panels
  //   [64M, 65M)      Wst  (dead after QK)     -- aliased by E
  //   [65M, 66M)      Wat  (dead after QK)     -- aliased by E
  //   [66M, 74M)      Wob  (dead after V')     -- head aliased by E (E = 71.3MB < 74M)
  //   [74M, 82M)      Qb
  //   [82M, 90M)      Kb
  //   [90M, 154M)     VT
  //   [154M, +64K)    lsum
  bf16_t* xb  = (bf16_t*)(ws + 0);
  bf16_t* Wst = (bf16_t*)(ws + 67108864);
  bf16_t* Wat = (bf16_t*)(ws + 68157440);
  bf16_t* Wob = (bf16_t*)(ws + 69206016);
  bf16_t* Qb  = (bf16_t*)(ws + 77594624);
  bf16_t* Kb  = (bf16_t*)(ws + 85983232);
  bf16_t* VT  = (bf16_t*)(ws + 94371840);
  float*  lsum = (float*)(ws + 161480704);
  bf16_t* E   = (bf16_t*)(ws + 0);

  hipFuncSetAttribute((const void*)vq8_kernel, hipFuncAttributeMaxDynamicSharedMemorySize, 131072);
  hipFuncSetAttribute((const void*)ep8_kernel, hipFuncAttributeMaxDynamicSharedMemorySize, 131072);
  hipFuncSetAttribute((const void*)pv8_kernel, hipFuncAttributeMaxDynamicSharedMemorySize, 131072);

  // fused conversions + lsum init
  conv_kernel<<<dim3(2048), dim3(256), 0, stream>>>(x, Ws, Wa, Wo, xb, Wst, Wat, Wob, lsum);
  // fused: Q = x @ Ws, K = x @ Wa (1/16 folded into EXP_SC) + V'^T = Wo . x
  vq8_kernel<<<dim3(640), dim3(512), 131072, stream>>>(Wob, xb, VT, Wst, Wat, Qb, Kb);
  // pass 1: E = exp(QK^T/16) causal pair-panels + row sums (E aliases xb/W* — all dead now)
  ep8_kernel<<<dim3(544), dim3(512), 131072, stream>>>(Qb, Kb, E, lsum);
  // pass 2: out = E @ V'^T / l + bo  (XCD-swizzled flat grid)
  pv8_kernel<<<dim3(256), dim3(512), 131072, stream>>>(E, VT, lsum, bo, out);
}

// Round 7
// 374.310 us; speedup vs baseline: 4.0740x; 1.0257x over previous
//
#include <hip/hip_runtime.h>
#include <hip/hip_bf16.h>
#include <cstdint>
#include <cstddef>
#include <cmath>

typedef __bf16 bf16_t;
typedef __bf16 bf16x8 __attribute__((ext_vector_type(8)));
typedef __bf16 bf16x4v __attribute__((ext_vector_type(4)));
typedef float f32x4 __attribute__((ext_vector_type(4)));

#define B_SZ 4
#define L_SZ 4096
#define H_SZ 2048
#define R_SZ 256
// exp(S) with S = acc/16  ->  2^(acc * log2(e)/16)
#define EXP_SC 0.090168440f
// E pair-panel geometry: pair P holds 256 rows x (P+1)*256 cols bf16
#define E2_ELEMS 8912896L   // 65536 * (1+2+...+16) elements per batch
#define E2_BYTES 17825792L

// async global->LDS, 16B per lane. LDS dest must be wave-uniform base (+lane*16 by HW).
#define GLDS16(gaddr, laddr)                                                    \
  __builtin_amdgcn_global_load_lds(                                             \
      (const __attribute__((address_space(1))) void*)(gaddr),                   \
      (__attribute__((address_space(3))) void*)(laddr), 16, 0, 0)

__device__ __forceinline__ f32x4 mfma16(bf16x8 a, bf16x8 b, f32x4 c) {
  return __builtin_amdgcn_mfma_f32_16x16x32_bf16(a, b, c, 0, 0, 0);
}

__device__ __forceinline__ float rsum16(float v) {
  v += __shfl_xor(v, 1, 16);
  v += __shfl_xor(v, 2, 16);
  v += __shfl_xor(v, 4, 16);
  v += __shfl_xor(v, 8, 16);
  return v;
}

// ---------------- fused conversion kernel ----------------
__global__ void conv_kernel(const float* __restrict__ x, const float* __restrict__ Ws,
                            const float* __restrict__ Wa, const float* __restrict__ Wo,
                            bf16_t* __restrict__ xb, bf16_t* __restrict__ Wst,
                            bf16_t* __restrict__ Wat, bf16_t* __restrict__ Wob,
                            float* __restrict__ lsum) {
  const int tid = blockIdx.x * blockDim.x + threadIdx.x;
  const int stride = gridDim.x * blockDim.x;
  const int n4 = B_SZ * L_SZ * H_SZ / 4;
  for (int i = tid; i < n4; i += stride) {
    float4 v = reinterpret_cast<const float4*>(x)[i];
    bf16x4v o;
    o[0] = (bf16_t)v.x; o[1] = (bf16_t)v.y; o[2] = (bf16_t)v.z; o[3] = (bf16_t)v.w;
    reinterpret_cast<bf16x4v*>(xb)[i] = o;
  }
  // transpose [H, R] -> [R, H]
  for (int idx = tid; idx < R_SZ * H_SZ; idx += stride) {
    const int rr = idx >> 11;
    const int h  = idx & (H_SZ - 1);
    Wst[idx] = (bf16_t)Ws[h * R_SZ + rr];
    Wat[idx] = (bf16_t)Wa[h * R_SZ + rr];
  }
  for (int idx = tid; idx < H_SZ * H_SZ; idx += stride) {
    Wob[idx] = (bf16_t)Wo[idx];
  }
  for (int idx = tid; idx < B_SZ * L_SZ; idx += stride) lsum[idx] = 0.0f;
}

// ================= 256x256 GEMM core — 2-barrier overlapped tile (R7) =================
// C[m,n] = sum_k A[m,k] B[n,k], A row-major [256 rows from Ag], B row-major [256 rows from Bg],
// K = NT*64 (NT even, >= 4). 512 threads = 8 waves (2M x 4N). LDS 128 KiB dynamic.
// m-frag am (0..7) -> rows wr*16 + am*32 (+0..15); n-frag an (0..3) -> cols wc*16 + an*64 (+0..15).
// LDS: A region [0,64K): buf(32K) x half(16K); B region [64K,128K). Linear [128 rows][128 B] per
// half-slot, swizzle realized by pre-swizzled global source; reads XOR the same mask.
//
// Sync design (only 2 barriers per K-tile — everything else free-runs so the LDS drain
// (~2260 cyc/tile @85 B/cyc) hides under the MFMA clusters (~2480 cyc/tile)):
//  region 1: reads A0,B0,B1 + stages A1/B1(T+1)->OTH.h1 (OTH last read at tile T-1: safe),
//            MFMA MH0x{NH0,NH1}, then A1 reads (compiler interleaves as fa regs die).
//            lgkmcnt(8): all MFMAs issued => A0/B0/B1 reads provably complete; only the 8
//            A1 reads may remain in flight. barrier => h0-slot reads done chip-wide.
//  region 2: stages A0/B0(T+2)->CUR.h0 (safe per barrier), MFMA MH1x{NH0,NH1}.
//            lgkmcnt(0) (A1 reads done) + vmcnt(4) (tile T+1 fully landed, A0/B0(T+2)
//            still in flight) + barrier => h1-slot reads done before T+1's early stages.
// Accumulation order identical to the verified R6 core (bit-identical results).

#define G8_STG(P, REGION, BUFOFF, HALF)                                        \
  GLDS16((P)[0], lds + (REGION) + (BUFOFF) + (HALF)*16384 + ldst0);            \
  GLDS16((P)[1], lds + (REGION) + (BUFOFF) + (HALF)*16384 + ldst1);            \
  (P)[0] += 128; (P)[1] += 128;

#define G8_LDA(MH, BO) {                                                       \
  const char* ap_ = lds + (BO) + (MH)*16384;                                   \
  fa[0][0] = *(const bf16x8*)(ap_ + aOff0);                                    \
  fa[0][1] = *(const bf16x8*)(ap_ + aOff1);                                    \
  fa[1][0] = *(const bf16x8*)(ap_ + 4096 + aOff0);                             \
  fa[1][1] = *(const bf16x8*)(ap_ + 4096 + aOff1);                             \
  fa[2][0] = *(const bf16x8*)(ap_ + 8192 + aOff0);                             \
  fa[2][1] = *(const bf16x8*)(ap_ + 8192 + aOff1);                             \
  fa[3][0] = *(const bf16x8*)(ap_ + 12288 + aOff0);                            \
  fa[3][1] = *(const bf16x8*)(ap_ + 12288 + aOff1); }

#define G8_LDB(NH, BO) {                                                       \
  const char* bp_ = lds + 65536 + (BO) + (NH)*16384;                           \
  fb[NH][0][0] = *(const bf16x8*)(bp_ + bOff0);                                \
  fb[NH][0][1] = *(const bf16x8*)(bp_ + bOff1);                                \
  fb[NH][1][0] = *(const bf16x8*)(bp_ + 8192 + bOff0);                         \
  fb[NH][1][1] = *(const bf16x8*)(bp_ + 8192 + bOff1); }

#define G8_MM1(AM, AN, MF, NH, J)                                              \
  acc[AM][AN] = mfma16(fa[MF][1], fb[NH][J][1],                                \
                 mfma16(fa[MF][0], fb[NH][J][0], acc[AM][AN]))

#define G8_MM(MH, NH)                                                          \
  G8_MM1((MH)*4+0, (NH)*2+0, 0, NH, 0); G8_MM1((MH)*4+0, (NH)*2+1, 0, NH, 1); \
  G8_MM1((MH)*4+1, (NH)*2+0, 1, NH, 0); G8_MM1((MH)*4+1, (NH)*2+1, 1, NH, 1); \
  G8_MM1((MH)*4+2, (NH)*2+0, 2, NH, 0); G8_MM1((MH)*4+2, (NH)*2+1, 2, NH, 1); \
  G8_MM1((MH)*4+3, (NH)*2+0, 3, NH, 0); G8_MM1((MH)*4+3, (NH)*2+1, 3, NH, 1)

// region 1: LOADS16 = A0+B0+B1 reads; S1 = stages into OTH.h1; then MFMA MH0, A1 reads.
#define G8_REGION1(BO, S1A, S1B)                                               \
  G8_LDA(0, BO);                                                               \
  G8_LDB(0, BO);                                                               \
  G8_LDB(1, BO);                                                               \
  S1A; S1B;                                                                    \
  __builtin_amdgcn_s_setprio(1);                                               \
  G8_MM(0, 0);                                                                 \
  G8_MM(0, 1);                                                                 \
  __builtin_amdgcn_s_setprio(0);                                               \
  G8_LDA(1, BO);                                                               \
  asm volatile("s_waitcnt lgkmcnt(8)" ::: "memory");                           \
  __builtin_amdgcn_sched_barrier(0);                                           \
  __builtin_amdgcn_s_barrier();

// region 2: S2 = stages into CUR.h0; MFMA MH1; WAITS = vmcnt; end barrier.
#define G8_REGION2(S2A, S2B, WAITS)                                            \
  S2A; S2B;                                                                    \
  __builtin_amdgcn_s_setprio(1);                                               \
  G8_MM(1, 0);                                                                 \
  G8_MM(1, 1);                                                                 \
  __builtin_amdgcn_s_setprio(0);                                               \
  asm volatile("s_waitcnt lgkmcnt(0)" ::: "memory");                           \
  WAITS;                                                                       \
  __builtin_amdgcn_sched_barrier(0);                                           \
  __builtin_amdgcn_s_barrier();

__device__ __forceinline__ void gemm8_core(
    const char* Ag, const char* Bg, long aRowB, long bRowB, int NT,
    char* lds, f32x4 (&acc)[8][4])
{
  const int t = threadIdx.x;
  const int l = t & 63;
  const int wid = t >> 6;
  const int wr = wid >> 2;
  const int wc = wid & 3;
  const int l15 = l & 15;
  const int l4 = l >> 4;
  const int swzm = (l15 & 7) << 4;
  const int aOff0 = (wr * 16 + l15) * 128 + ((l4 * 16) ^ swzm);
  const int aOff1 = (wr * 16 + l15) * 128 + ((64 + l4 * 16) ^ swzm);
  const int bOff0 = (wc * 16 + l15) * 128 + ((l4 * 16) ^ swzm);
  const int bOff1 = (wc * 16 + l15) * 128 + ((64 + l4 * 16) ^ swzm);
  // staging: per-thread, 2 x 16B per half-tile; d = t*16 + i*8192 covers [0,16K) linear
  const int d0 = t * 16, d1 = t * 16 + 8192;
  const int r0 = d0 >> 7, r1 = d1 >> 7;
  const int s0 = (d0 & 127) ^ ((r0 & 7) << 4);
  const int s1 = (d1 & 127) ^ ((r1 & 7) << 4);
  const char* pA0[2] = { Ag + (long)r0 * aRowB + s0, Ag + (long)r1 * aRowB + s1 };
  const char* pA1[2] = { Ag + (long)(128 + r0) * aRowB + s0, Ag + (long)(128 + r1) * aRowB + s1 };
  const char* pB0[2] = { Bg + (long)r0 * bRowB + s0, Bg + (long)r1 * bRowB + s1 };
  const char* pB1[2] = { Bg + (long)(128 + r0) * bRowB + s0, Bg + (long)(128 + r1) * bRowB + s1 };
  const int ldst0 = wid * 1024, ldst1 = wid * 1024 + 8192;
  bf16x8 fa[4][2], fb[2][2][2];

  // prologue: stage tile0 (A0,B0,A1,B1) + tile1 (A0,B0); wait tile0; barrier
  G8_STG(pA0, 0, 0, 0);
  G8_STG(pB0, 65536, 0, 0);
  G8_STG(pA1, 0, 0, 1);
  G8_STG(pB1, 65536, 0, 1);
  G8_STG(pA0, 0, 32768, 0);
  G8_STG(pB0, 65536, 32768, 0);
  asm volatile("s_waitcnt vmcnt(4)" ::: "memory");
  __builtin_amdgcn_sched_barrier(0);
  __builtin_amdgcn_s_barrier();

  int bufOff = 0;
  for (int T = 0; T < NT - 2; ++T) {
    const int ob = bufOff ^ 32768;
    G8_REGION1(bufOff, G8_STG(pA1, 0, ob, 1), G8_STG(pB1, 65536, ob, 1));
    G8_REGION2(G8_STG(pA0, 0, bufOff, 0), G8_STG(pB0, 65536, bufOff, 0),
               asm volatile("s_waitcnt vmcnt(4)" ::: "memory"));
    bufOff ^= 32768;
  }
  // T = NT-2: stage only (NT-1).A1/B1; drain at region 2
  {
    const int ob = bufOff ^ 32768;
    G8_REGION1(bufOff, G8_STG(pA1, 0, ob, 1), G8_STG(pB1, 65536, ob, 1));
    G8_REGION2(, , asm volatile("s_waitcnt vmcnt(0)" ::: "memory"));
    bufOff ^= 32768;
  }
  // T = NT-1: compute only
  {
    G8_REGION1(bufOff, , );
    G8_REGION2(, , );
  }
}

// ---------------- fused V'+QK GEMM kernel ----------------
// Flat grid 640 blocks. f < 128: QK projection (proj = f>>6, mtile = f&63; short blocks first
// so the dispatcher fills CU tails). f >= 128: V' GEMM with XCD-chunked swizzle.
__global__ __launch_bounds__(512) void vq8_kernel(
    const bf16_t* __restrict__ Wob, const bf16_t* __restrict__ xb, bf16_t* __restrict__ VT,
    const bf16_t* __restrict__ Wst, const bf16_t* __restrict__ Wat,
    bf16_t* __restrict__ Qb, bf16_t* __restrict__ Kb)
{
  extern __shared__ char lds[];
  const int f = blockIdx.x;
  const int t = threadIdx.x, l = t & 63, wid = t >> 6;
  const int wr = wid >> 2, wc = wid & 3, l15 = l & 15, l4 = l >> 4;
  if (f < 128) {
    const int proj = f >> 6;
    const long mBase = (long)(f & 63) * 256;
    const bf16_t* W = proj ? Wat : Wst;
    bf16_t* Cp = proj ? Kb : Qb;
    f32x4 acc[8][4] = {};
    gemm8_core((const char*)xb + mBase * (H_SZ * 2), (const char*)W,
               H_SZ * 2, H_SZ * 2, H_SZ / 64, lds, acc);
#pragma unroll
    for (int am = 0; am < 8; ++am) {
#pragma unroll
      for (int an = 0; an < 4; ++an) {
        const long row = mBase + wr * 16 + am * 32 + l4 * 4;
        const int col = wc * 16 + an * 64 + l15;
#pragma unroll
        for (int r = 0; r < 4; ++r)
          Cp[(row + r) * R_SZ + col] = (bf16_t)acc[am][an][r];
      }
    }
  } else {
    const int g = f - 128;                    // 0..511
    const int lg = (g & 7) * 64 + (g >> 3);   // bijective (512 = 8*64)
    const int xo = lg & 7;
    const int yj = (lg >> 3) & 15;
    const int b  = lg >> 7;
    const long mBase = (long)xo * 256;        // o
    const long nBase = (long)yj * 256;        // j
    f32x4 acc[8][4] = {};
    gemm8_core((const char*)Wob + mBase * (H_SZ * 2),
               (const char*)xb + ((long)b * L_SZ + nBase) * (H_SZ * 2),
               H_SZ * 2, H_SZ * 2, H_SZ / 64, lds, acc);
    bf16_t* Cp = VT + (long)b * H_SZ * L_SZ;
#pragma unroll
    for (int am = 0; am < 8; ++am) {
#pragma unroll
      for (int an = 0; an < 4; ++an) {
        const long row = mBase + wr * 16 + am * 32 + l4 * 4;
        const long col = nBase + wc * 16 + an * 64 + l15;
#pragma unroll
        for (int r = 0; r < 4; ++r)
          Cp[(row + r) * L_SZ + col] = (bf16_t)acc[am][an][r];
      }
    }
  }
}

// ---------------- pass 1 (8-phase): E = exp(Q K^T / 16) (causal) pair-panels + row sums ----
// Flat grid 544 (= 4 b x 136 triangular tiles), XCD-chunked so same-Q-panel blocks share an L2.
__global__ __launch_bounds__(512) void ep8_kernel(
    const bf16_t* __restrict__ Qb, const bf16_t* __restrict__ Kb,
    bf16_t* __restrict__ E, float* __restrict__ lsum)
{
  extern __shared__ char lds[];
  const int f = blockIdx.x;                  // 0..543
  const int lg = (f & 7) * 68 + (f >> 3);    // bijective (544 = 8*68)
  const int b = lg / 136;
  const int t136 = lg - b * 136;
  int P = (int)((sqrtf((float)(8 * t136 + 1)) - 1.0f) * 0.5f);
  while ((P + 1) * (P + 2) / 2 <= t136) ++P;
  while (P * (P + 1) / 2 > t136) --P;
  const int Jp = t136 - P * (P + 1) / 2;     // 0..P

  f32x4 acc[8][4] = {};
  gemm8_core((const char*)Qb + ((long)b * L_SZ + P * 256) * (R_SZ * 2),
             (const char*)Kb + ((long)b * L_SZ + Jp * 256) * (R_SZ * 2),
             R_SZ * 2, R_SZ * 2, R_SZ / 64, lds, acc);
  const int t = threadIdx.x, l = t & 63, wid = t >> 6;
  const int wr = wid >> 2, wc = wid & 3, l15 = l & 15, l4 = l >> 4;
  bf16_t* Ep = E + (long)b * E2_ELEMS + 32768L * P * (P + 1);
  const long ldaE = (long)(P + 1) * 256;
  float* lp = lsum + (long)b * L_SZ + P * 256;
  const bool diag = (Jp == P);
#pragma unroll
  for (int am = 0; am < 8; ++am) {
    const int rowi = wr * 16 + am * 32 + l4 * 4;   // 0..255 within pair rows
#pragma unroll
    for (int r = 0; r < 4; ++r) {
      float s = 0.0f;
#pragma unroll
      for (int an = 0; an < 4; ++an) {
        const int coli = wc * 16 + an * 64 + l15;
        float p = exp2f(acc[am][an][r] * EXP_SC);
        if (diag && coli > rowi + r) p = 0.0f;     // jj > ii (same 256-tile)
        Ep[(long)(rowi + r) * ldaE + Jp * 256 + coli] = (bf16_t)p;
        s += p;
      }
      s = rsum16(s);
      if (l15 == 0) atomicAdd(lp + rowi + r, s);
    }
  }
}

// ---------------- pass 2: out = (E @ V'^T) / l + bo, paired tiles for balance ----------------
// Flat grid 256; XCD-chunked swizzle: each XCD gets 4 pr-pairs x 8 j-slices, one b.
__global__ __launch_bounds__(512) void pv8_kernel(
    const bf16_t* __restrict__ E, const bf16_t* __restrict__ VT,
    const float* __restrict__ lsum, const float* __restrict__ bo,
    float* __restrict__ out)
{
  extern __shared__ char lds[];
  const int f = blockIdx.x;                 // 0..255
  const int lg = (f & 7) * 32 + (f >> 3);   // bijective (256 = 8*32)
  const int yj = lg & 7;
  const int pr = (lg >> 3) & 7;
  const int b  = lg >> 6;
  const int nBase = yj * 256;
  const int t = threadIdx.x, l = t & 63, wid = t >> 6;
  const int wr = wid >> 2, wc = wid & 3, l15 = l & 15, l4 = l >> 4;

#pragma unroll
  for (int s = 0; s < 2; ++s) {
    const int mt = s ? pr : (15 - pr);
    f32x4 acc[8][4] = {};
    const char* Ag = (const char*)E + (long)b * E2_BYTES + 65536L * mt * (mt + 1);
    const char* Bg = (const char*)VT + ((long)b * H_SZ + nBase) * (L_SZ * 2);
    gemm8_core(Ag, Bg, (long)(mt + 1) * 512, L_SZ * 2, (mt + 1) * 4, lds, acc);
#pragma unroll
    for (int am = 0; am < 8; ++am) {
      const long rowG = (long)b * L_SZ + mt * 256 + wr * 16 + am * 32 + l4 * 4;
      float linv[4];
#pragma unroll
      for (int r = 0; r < 4; ++r) linv[r] = 1.0f / lsum[rowG + r];
#pragma unroll
      for (int an = 0; an < 4; ++an) {
        const int col = nBase + wc * 16 + an * 64 + l15;
        const float bias = bo[col];
#pragma unroll
        for (int r = 0; r < 4; ++r)
          out[(rowG + r) * H_SZ + col] = acc[am][an][r] * linv[r] + bias;
      }
    }
  }
}

extern "C" void kernel_launch(void* const* d_in, const int* in_sizes, int n_in,
                              void* d_out, int out_size, void* d_ws, size_t ws_size,
                              hipStream_t stream) {
  const float* x  = (const float*)d_in[0];
  const float* Ws = (const float*)d_in[1];
  const float* Wa = (const float*)d_in[2];
  const float* Wo = (const float*)d_in[3];
  const float* bo = (const float*)d_in[4];
  float* out = (float*)d_out;

  char* ws = (char*)d_ws;
  // layout (bytes):
  //   [0, 64M)        xb   (dead after V'/QK)  -- aliased by E pair-panels
  //   [64M, 65M)      Wst  (dead after QK)     -- aliased by E
  //   [65M, 66M)      Wat  (dead after QK)     -- aliased by E
  //   [66M, 74M)      Wob  (dead after V')     -- head aliased by E (E = 71.3MB < 74M)
  //   [74M, 82M)      Qb
  //   [82M, 90M)      Kb
  //   [90M, 154M)     VT
  //   [154M, +64K)    lsum
  bf16_t* xb  = (bf16_t*)(ws + 0);
  bf16_t* Wst = (bf16_t*)(ws + 67108864);
  bf16_t* Wat = (bf16_t*)(ws + 68157440);
  bf16_t* Wob = (bf16_t*)(ws + 69206016);
  bf16_t* Qb  = (bf16_t*)(ws + 77594624);
  bf16_t* Kb  = (bf16_t*)(ws + 85983232);
  bf16_t* VT  = (bf16_t*)(ws + 94371840);
  float*  lsum = (float*)(ws + 161480704);
  bf16_t* E   = (bf16_t*)(ws + 0);

  hipFuncSetAttribute((const void*)vq8_kernel, hipFuncAttributeMaxDynamicSharedMemorySize, 131072);
  hipFuncSetAttribute((const void*)ep8_kernel, hipFuncAttributeMaxDynamicSharedMemorySize, 131072);
  hipFuncSetAttribute((const void*)pv8_kernel, hipFuncAttributeMaxDynamicSharedMemorySize, 131072);

  // fused conversions + lsum init
  conv_kernel<<<dim3(2048), dim3(256), 0, stream>>>(x, Ws, Wa, Wo, xb, Wst, Wat, Wob, lsum);
  // fused: Q = x @ Ws, K = x @ Wa (1/16 folded into EXP_SC) + V'^T = Wo . x
  vq8_kernel<<<dim3(640), dim3(512), 131072, stream>>>(Wob, xb, VT, Wst, Wat, Qb, Kb);
  // pass 1: E = exp(QK^T/16) causal pair-panels + row sums (E aliases xb/W* — all dead now)
  ep8_kernel<<<dim3(544), dim3(512), 131072, stream>>>(Qb, Kb, E, lsum);
  // pass 2: out = E @ V'^T / l + bo  (XCD-swizzled flat grid)
  pv8_kernel<<<dim3(256), dim3(512), 131072, stream>>>(E, VT, lsum, bo, out);
}